// Round 1
// baseline (6814.876 us; speedup 1.0000x reference)
//
#include <hip/hip_runtime.h>
#include <hip/hip_bf16.h>

typedef __attribute__((ext_vector_type(8))) short short8;
typedef __attribute__((ext_vector_type(4))) float f32x4;
typedef __hip_bfloat16 bf16;

#define AS1 __attribute__((address_space(1)))
#define AS3 __attribute__((address_space(3)))

__device__ __forceinline__ float b2f(short u) {
  union { unsigned int i; float f; } x;
  x.i = ((unsigned int)(unsigned short)u) << 16;
  return x.f;
}

__device__ __forceinline__ void gld_lds16(const void* g, void* lds) {
  __builtin_amdgcn_global_load_lds((const AS1 unsigned int*)g,
                                   (AS3 unsigned int*)lds, 16, 0, 0);
}

// ---------------- weight transpose + fp32->bf16 convert ----------------
// src: [L][R][C] fp32 ; dst: [L-stride][(row_off+n)*R + k] bf16  (i.e. [C][R] per layer)
__global__ void transpose_conv(const float* __restrict__ src, bf16* __restrict__ dst,
                               int R, int C, int row_off, long long layer_stride) {
  __shared__ float t[32][33];
  int l = blockIdx.z;
  int r0 = blockIdx.y * 32;   // src row (k)
  int c0 = blockIdx.x * 32;   // src col (n)
  int tx = threadIdx.x & 31, ty = threadIdx.x >> 5;
  const float* s = src + (size_t)l * R * C;
#pragma unroll
  for (int i = 0; i < 4; ++i)
    t[ty + i * 8][tx] = s[(size_t)(r0 + ty + i * 8) * C + c0 + tx];
  __syncthreads();
  bf16* d = dst + (size_t)l * layer_stride;
#pragma unroll
  for (int i = 0; i < 4; ++i) {
    int n = c0 + ty + i * 8, k = r0 + tx;
    d[(size_t)(row_off + n) * R + k] = __float2bfloat16(t[tx][ty + i * 8]);
  }
}

// ---------------- patch embed + pos embed -> x_s fp32 [B,256,768] ----------------
__global__ void patch_embed(const float* __restrict__ x, const float* __restrict__ pw,
                            const float* __restrict__ pb, const float* __restrict__ pos,
                            float* __restrict__ xs) {
  int idx = blockIdx.x * 256 + threadIdx.x;     // [B][N][D]
  int d = idx % 768;
  int n = (idx / 768) & 255;
  int b = idx / (768 * 256);
  int gi = n >> 4, gj = n & 15;
  float acc = pb[d];
#pragma unroll
  for (int c = 0; c < 4; ++c)
#pragma unroll
    for (int p = 0; p < 2; ++p)
#pragma unroll
      for (int q = 0; q < 2; ++q)
        acc += x[((b * 4 + c) * 32 + gi * 2 + p) * 32 + gj * 2 + q] *
               pw[((d * 4 + c) * 2 + p) * 2 + q];
  xs[idx] = acc + pos[n * 768 + d];
}

// ---------------- time embedding ----------------
__global__ void temb_kernel(const float* __restrict__ t, float* __restrict__ emb) {
  int b = blockIdx.x;
  int i = threadIdx.x;                          // 128 threads
  float f = __expf((float)i * (-logf(10000.f) / 127.f));
  float e = t[b] * f;
  emb[b * 256 + i] = sinf(e);
  emb[b * 256 + 128 + i] = cosf(e);
}

__global__ void smallmm(const float* __restrict__ in, const float* __restrict__ w,
                        const float* __restrict__ bias, float* __restrict__ out,
                        int K, int dosilu) {
  int idx = blockIdx.x * 256 + threadIdx.x;     // [32][768]
  int d = idx % 768, b = idx / 768;
  float a = bias[d];
  const float* ir = in + b * K;
  for (int k = 0; k < K; ++k) a += ir[k] * w[k * 768 + d];
  if (dosilu) a = a / (1.f + __expf(-a));
  out[idx] = a;
}

// per-layer time tokens: ttok[l][s][b][d] = x_t[b] @ w{q,k,v}t[l] + b{q,k,v}t[l]
__global__ void ttok_kernel(const float* __restrict__ xt,
                            const float* __restrict__ wqt, const float* __restrict__ bqt,
                            const float* __restrict__ wkt, const float* __restrict__ bkt,
                            const float* __restrict__ wvt, const float* __restrict__ bvt,
                            float* __restrict__ ttok) {
  int idx = blockIdx.x * 256 + threadIdx.x;     // [12][3][32][768]
  int d = idx % 768;
  int b = (idx / 768) & 31;
  int s = (idx / (768 * 32)) % 3;
  int l = idx / (768 * 32 * 3);
  const float* w = (s == 0 ? wqt : s == 1 ? wkt : wvt) + (size_t)l * 768 * 768;
  const float* bb = (s == 0 ? bqt : s == 1 ? bkt : bvt) + l * 768;
  float a = bb[d];
  const float* xr = xt + b * 768;
  for (int k = 0; k < 768; ++k) a += xr[k] * w[k * 768 + d];
  ttok[idx] = a;
}

// ---------------- LayerNorm fp32 -> bf16 ----------------
__global__ __launch_bounds__(256) void ln_bf16_kernel(const float* __restrict__ x,
                                                      const float* __restrict__ w,
                                                      const float* __restrict__ b,
                                                      bf16* __restrict__ out) {
  int row = blockIdx.x;
  int tid = threadIdx.x;
  const float* xr = x + (size_t)row * 768;
  float v[3];
  float s = 0.f, s2 = 0.f;
#pragma unroll
  for (int i = 0; i < 3; ++i) {
    v[i] = xr[tid + i * 256];
    s += v[i];
    s2 += v[i] * v[i];
  }
#pragma unroll
  for (int off = 32; off; off >>= 1) {
    s += __shfl_down(s, off);
    s2 += __shfl_down(s2, off);
  }
  __shared__ float ps[4], ps2[4];
  int wid = tid >> 6, lane = tid & 63;
  if (lane == 0) { ps[wid] = s; ps2[wid] = s2; }
  __syncthreads();
  s = ps[0] + ps[1] + ps[2] + ps[3];
  s2 = ps2[0] + ps2[1] + ps2[2] + ps2[3];
  float m = s * (1.f / 768.f);
  float var = s2 * (1.f / 768.f) - m * m;
  float r = rsqrtf(var + 1e-6f);
#pragma unroll
  for (int i = 0; i < 3; ++i) {
    int c = tid + i * 256;
    out[(size_t)row * 768 + c] = __float2bfloat16((v[i] - m) * r * w[c] + b[c]);
  }
}

// ---------------- MFMA GEMM: C[M,N] = A[M,K](bf16) * BT[N,K](bf16)^T + epilogue ----------------
// 128x128 tile, 4 waves (each 64x64 = 4x4 frags of 16x16x32), global_load_lds staging.
// EPI 0: out bf16 = acc + bias{q,k,v}[d] + ttok{q,k,v}[b][d]   (QKV packed, ldc=2304)
// EPI 1: out fp32 = acc + bias[col] + resid[row,col]           (proj / mlp2 residual)
// EPI 2: out bf16 = silu(acc + bias[col])                      (mlp1)
template <int EPI>
__global__ __launch_bounds__(256) void gemm128(
    const bf16* __restrict__ A, int lda, const bf16* __restrict__ BT, int ldb, int K,
    const float* __restrict__ bias, const float* __restrict__ bias_k,
    const float* __restrict__ bias_v, const float* __restrict__ tq,
    const float* __restrict__ tk, const float* __restrict__ tv,
    const float* __restrict__ resid, float* __restrict__ outF,
    bf16* __restrict__ outB, int ldc) {
  __shared__ bf16 As[128 * 32];
  __shared__ bf16 Bs[128 * 32];
  const int tid = threadIdx.x;
  const int wid = tid >> 6, lane = tid & 63;
  const int wr = wid >> 1, wc = wid & 1;
  const int m0 = blockIdx.y * 128, n0 = blockIdx.x * 128;
  const int l16 = lane & 15, lq = lane >> 4;

  f32x4 acc[4][4];
#pragma unroll
  for (int i = 0; i < 4; ++i)
#pragma unroll
    for (int j = 0; j < 4; ++j) acc[i][j] = f32x4{0.f, 0.f, 0.f, 0.f};

  const int r2 = tid >> 2, c2 = tid & 3;       // 64 rows / issue, 4 x 16B per row
  const bf16* ga0 = A + (size_t)(m0 + r2) * lda + c2 * 8;
  const bf16* ga1 = A + (size_t)(m0 + 64 + r2) * lda + c2 * 8;
  const bf16* gb0 = BT + (size_t)(n0 + r2) * ldb + c2 * 8;
  const bf16* gb1 = BT + (size_t)(n0 + 64 + r2) * ldb + c2 * 8;
  const unsigned wb = (unsigned)((tid & ~63) * 16);
  const unsigned offw = (unsigned)__builtin_amdgcn_readfirstlane(wb);
  char* AsB = (char*)As;
  char* BsB = (char*)Bs;

  for (int k0 = 0; k0 < K; k0 += 32) {
    gld_lds16(ga0 + k0, AsB + offw);
    gld_lds16(ga1 + k0, AsB + 4096 + offw);
    gld_lds16(gb0 + k0, BsB + offw);
    gld_lds16(gb1 + k0, BsB + 4096 + offw);
    asm volatile("s_waitcnt vmcnt(0)" ::: "memory");
    __syncthreads();
    short8 af[4], bfr[4];
#pragma unroll
    for (int i = 0; i < 4; ++i) {
      int ar = wr * 64 + i * 16 + l16;
      af[i] = *(const short8*)(AsB + ar * 64 + lq * 16);
      int br = wc * 64 + i * 16 + l16;
      bfr[i] = *(const short8*)(BsB + br * 64 + lq * 16);
    }
#pragma unroll
    for (int i = 0; i < 4; ++i)
#pragma unroll
      for (int j = 0; j < 4; ++j)
        acc[i][j] = __builtin_amdgcn_mfma_f32_16x16x32_bf16(af[i], bfr[j], acc[i][j], 0, 0, 0);
    __syncthreads();
  }

#pragma unroll
  for (int i = 0; i < 4; ++i) {
#pragma unroll
    for (int j = 0; j < 4; ++j) {
#pragma unroll
      for (int r = 0; r < 4; ++r) {
        int row = m0 + wr * 64 + i * 16 + lq * 4 + r;
        int col = n0 + wc * 64 + j * 16 + l16;
        float v = acc[i][j][r];
        if constexpr (EPI == 0) {
          int s = col / 768, d = col % 768;
          int b = row >> 8;
          const float* bs = (s == 0) ? bias : (s == 1) ? bias_k : bias_v;
          const float* ts = (s == 0) ? tq : (s == 1) ? tk : tv;
          v += bs[d] + ts[b * 768 + d];
          outB[(size_t)row * ldc + col] = __float2bfloat16(v);
        } else if constexpr (EPI == 1) {
          v += bias[col] + resid[(size_t)row * ldc + col];
          outF[(size_t)row * ldc + col] = v;
        } else {
          v += bias[col];
          v = v / (1.f + __expf(-v));
          outB[(size_t)row * ldc + col] = __float2bfloat16(v);
        }
      }
    }
  }
}

// ---------------- attention: per-thread online-softmax flash ----------------
// block = (b,h); 256 threads, one q-row each. K,V staged bf16 in LDS (64KB).
__global__ __launch_bounds__(256) void attn_kernel(const bf16* __restrict__ qkv,
                                                   const float* __restrict__ rpb_l,
                                                   bf16* __restrict__ obuf) {
  __shared__ short8 Ks[2048];
  __shared__ short8 Vs[2048];
  int tid = threadIdx.x;
  int b = blockIdx.x / 12, h = blockIdx.x % 12;
  const short8* base = (const short8*)qkv + (size_t)b * 256 * 288;   // row stride 2304/8=288
  int koff = 96 + h * 8;        // (768 + h*64)/8
  int voff = koff + 96;         // +768/8
#pragma unroll
  for (int it = 0; it < 8; ++it) {
    int v = it * 256 + tid;
    int row = v >> 3, c = v & 7;
    Ks[v] = base[row * 288 + koff + c];
    Vs[v] = base[row * 288 + voff + c];
  }
  float qf[64];
  {
    const short8* qrow = base + tid * 288 + h * 8;
#pragma unroll
    for (int c = 0; c < 8; ++c) {
      short8 qq = qrow[c];
#pragma unroll
      for (int j = 0; j < 8; ++j) qf[c * 8 + j] = b2f(qq[j]);
    }
  }
  __syncthreads();
  int qr = tid >> 4, qc = tid & 15;
  float O[64];
#pragma unroll
  for (int j = 0; j < 64; ++j) O[j] = 0.f;
  float m = -1e30f, l = 0.f;
  for (int k = 0; k < 256; ++k) {
    float s = 0.f;
#pragma unroll
    for (int c = 0; c < 8; ++c) {
      short8 kk = Ks[k * 8 + c];
#pragma unroll
      for (int j = 0; j < 8; ++j) s += qf[c * 8 + j] * b2f(kk[j]);
    }
    int kr = k >> 4, kc = k & 15;
    s = s * 0.125f + rpb_l[((qr - kr + 15) * 31 + (qc - kc + 15)) * 12 + h];
    if (s > m) {
      float corr = __expf(m - s);
      l *= corr;
#pragma unroll
      for (int j = 0; j < 64; ++j) O[j] *= corr;
      m = s;
    }
    float p = __expf(s - m);
    l += p;
#pragma unroll
    for (int c = 0; c < 8; ++c) {
      short8 vv = Vs[k * 8 + c];
#pragma unroll
      for (int j = 0; j < 8; ++j) O[c * 8 + j] += p * b2f(vv[j]);
    }
  }
  float inv = 1.f / l;
  bf16* orow = obuf + (size_t)b * 256 * 768 + (size_t)tid * 768 + h * 64;
#pragma unroll
  for (int j = 0; j < 64; ++j) orow[j] = __float2bfloat16(O[j] * inv);
}

// ---------------- final decode + unpatchify ----------------
__global__ void decode_kernel(const bf16* __restrict__ hf, const float* __restrict__ dw,
                              const float* __restrict__ db, float* __restrict__ out) {
  int o = blockIdx.x * 256 + threadIdx.x;       // [B][C][32][32] = 131072
  int x2 = o & 31, y = (o >> 5) & 31, c = (o >> 10) & 3, b = o >> 12;
  int gi = y >> 1, p = y & 1, gj = x2 >> 1, q = x2 & 1;
  int n = gi * 16 + gj;
  int j = (c * 2 + p) * 2 + q;
  const bf16* hr = hf + (size_t)(b * 256 + n) * 768;
  float a = db[j];
  for (int k = 0; k < 768; ++k) a += __bfloat162float(hr[k]) * dw[k * 16 + j];
  out[o] = a;
}

extern "C" void kernel_launch(void* const* d_in, const int* in_sizes, int n_in,
                              void* d_out, int out_size, void* d_ws, size_t ws_size,
                              hipStream_t stream) {
  (void)in_sizes; (void)n_in; (void)out_size; (void)ws_size;
  const float* x       = (const float*)d_in[0];
  const float* t_in    = (const float*)d_in[1];
  const float* patch_w = (const float*)d_in[2];
  const float* patch_b = (const float*)d_in[3];
  const float* pos     = (const float*)d_in[4];
  const float* t_w1    = (const float*)d_in[5];
  const float* t_b1    = (const float*)d_in[6];
  const float* t_w2    = (const float*)d_in[7];
  const float* t_b2    = (const float*)d_in[8];
  const float* norm1_w = (const float*)d_in[9];
  const float* norm1_b = (const float*)d_in[10];
  const float* wqs     = (const float*)d_in[11];
  const float* bqs     = (const float*)d_in[12];
  const float* wqt     = (const float*)d_in[13];
  const float* bqt     = (const float*)d_in[14];
  const float* wks     = (const float*)d_in[15];
  const float* bks     = (const float*)d_in[16];
  const float* wkt     = (const float*)d_in[17];
  const float* bkt     = (const float*)d_in[18];
  const float* wvs     = (const float*)d_in[19];
  const float* bvs     = (const float*)d_in[20];
  const float* wvt     = (const float*)d_in[21];
  const float* bvt     = (const float*)d_in[22];
  const float* projw   = (const float*)d_in[23];
  const float* projb   = (const float*)d_in[24];
  const float* rpb     = (const float*)d_in[25];
  const float* norm2_w = (const float*)d_in[26];
  const float* norm2_b = (const float*)d_in[27];
  const float* mlp_w1  = (const float*)d_in[28];
  const float* mlp_b1  = (const float*)d_in[29];
  const float* mlp_w2  = (const float*)d_in[30];
  const float* mlp_b2  = (const float*)d_in[31];
  const float* norm_w  = (const float*)d_in[32];
  const float* norm_b  = (const float*)d_in[33];
  const float* dec_w   = (const float*)d_in[34];
  const float* dec_b   = (const float*)d_in[35];

  char* ws = (char*)d_ws;
  size_t off = 0;
  auto alloc = [&](size_t bytes) -> void* {
    void* p = ws + off;
    off += (bytes + 255) & ~(size_t)255;
    return p;
  };
  bf16* wqkvT = (bf16*)alloc(12ull * 2304 * 768 * 2);
  bf16* projT = (bf16*)alloc(12ull * 768 * 768 * 2);
  bf16* mlp1T = (bf16*)alloc(12ull * 3072 * 768 * 2);
  bf16* mlp2T = (bf16*)alloc(12ull * 768 * 3072 * 2);
  float* xs   = (float*)alloc(8192ull * 768 * 4);
  bf16* hbuf  = (bf16*)alloc(8192ull * 768 * 2);
  bf16* qkvb  = (bf16*)alloc(8192ull * 2304 * 2);
  bf16* obuf  = (bf16*)alloc(8192ull * 768 * 2);
  bf16* hmlp  = (bf16*)alloc(8192ull * 3072 * 2);
  float* emb  = (float*)alloc(32ull * 256 * 4);
  float* h1   = (float*)alloc(32ull * 768 * 4);
  float* xt   = (float*)alloc(32ull * 768 * 4);
  float* ttok = (float*)alloc(12ull * 3 * 32 * 768 * 4);

  // weight conversion (every call; ~100us of BW)
  transpose_conv<<<dim3(24, 24, 12), 256, 0, stream>>>(wqs, wqkvT, 768, 768, 0, 2304ll * 768);
  transpose_conv<<<dim3(24, 24, 12), 256, 0, stream>>>(wks, wqkvT, 768, 768, 768, 2304ll * 768);
  transpose_conv<<<dim3(24, 24, 12), 256, 0, stream>>>(wvs, wqkvT, 768, 768, 1536, 2304ll * 768);
  transpose_conv<<<dim3(24, 24, 12), 256, 0, stream>>>(projw, projT, 768, 768, 0, 768ll * 768);
  transpose_conv<<<dim3(96, 24, 12), 256, 0, stream>>>(mlp_w1, mlp1T, 768, 3072, 0, 3072ll * 768);
  transpose_conv<<<dim3(24, 96, 12), 256, 0, stream>>>(mlp_w2, mlp2T, 3072, 768, 0, 768ll * 3072);

  // time embedding chain + per-layer time tokens
  temb_kernel<<<32, 128, 0, stream>>>(t_in, emb);
  smallmm<<<96, 256, 0, stream>>>(emb, t_w1, t_b1, h1, 256, 1);
  smallmm<<<96, 256, 0, stream>>>(h1, t_w2, t_b2, xt, 768, 0);
  ttok_kernel<<<3456, 256, 0, stream>>>(xt, wqt, bqt, wkt, bkt, wvt, bvt, ttok);

  // patch embed
  patch_embed<<<24576, 256, 0, stream>>>(x, patch_w, patch_b, pos, xs);

  for (int l = 0; l < 12; ++l) {
    ln_bf16_kernel<<<8192, 256, 0, stream>>>(xs, norm1_w + l * 768, norm1_b + l * 768, hbuf);
    gemm128<0><<<dim3(18, 64), 256, 0, stream>>>(
        hbuf, 768, wqkvT + (size_t)l * 2304 * 768, 768, 768,
        bqs + l * 768, bks + l * 768, bvs + l * 768,
        ttok + (size_t)(l * 3 + 0) * 32 * 768,
        ttok + (size_t)(l * 3 + 1) * 32 * 768,
        ttok + (size_t)(l * 3 + 2) * 32 * 768,
        nullptr, nullptr, qkvb, 2304);
    attn_kernel<<<384, 256, 0, stream>>>(qkvb, rpb + (size_t)l * 31 * 31 * 12, obuf);
    gemm128<1><<<dim3(6, 64), 256, 0, stream>>>(
        obuf, 768, projT + (size_t)l * 768 * 768, 768, 768,
        projb + l * 768, nullptr, nullptr, nullptr, nullptr, nullptr,
        xs, xs, nullptr, 768);
    ln_bf16_kernel<<<8192, 256, 0, stream>>>(xs, norm2_w + l * 768, norm2_b + l * 768, hbuf);
    gemm128<2><<<dim3(24, 64), 256, 0, stream>>>(
        hbuf, 768, mlp1T + (size_t)l * 3072 * 768, 768, 768,
        mlp_b1 + l * 3072, nullptr, nullptr, nullptr, nullptr, nullptr,
        nullptr, nullptr, hmlp, 3072);
    gemm128<1><<<dim3(6, 64), 256, 0, stream>>>(
        hmlp, 3072, mlp2T + (size_t)l * 768 * 3072, 3072, 3072,
        mlp_b2 + l * 768, nullptr, nullptr, nullptr, nullptr, nullptr,
        xs, xs, nullptr, 768);
  }
  ln_bf16_kernel<<<8192, 256, 0, stream>>>(xs, norm_w, norm_b, hbuf);
  decode_kernel<<<512, 256, 0, stream>>>(hbuf, dec_w, dec_b, (float*)d_out);
}

// Round 2
// 4044.867 us; speedup vs baseline: 1.6848x; 1.6848x over previous
//
#include <hip/hip_runtime.h>
#include <hip/hip_bf16.h>

typedef __attribute__((ext_vector_type(8))) short short8;
typedef __attribute__((ext_vector_type(4))) float f32x4;
typedef __hip_bfloat16 bf16;

#define AS1 __attribute__((address_space(1)))
#define AS3 __attribute__((address_space(3)))

__device__ __forceinline__ float b2f(short u) {
  union { unsigned int i; float f; } x;
  x.i = ((unsigned int)(unsigned short)u) << 16;
  return x.f;
}

__device__ __forceinline__ void gld_lds16(const void* g, void* lds) {
  __builtin_amdgcn_global_load_lds((const AS1 unsigned int*)g,
                                   (AS3 unsigned int*)lds, 16, 0, 0);
}

// ---------------- weight transpose + fp32->bf16 convert ----------------
__global__ void transpose_conv(const float* __restrict__ src, bf16* __restrict__ dst,
                               int R, int C, int row_off, long long layer_stride) {
  __shared__ float t[32][33];
  int l = blockIdx.z;
  int r0 = blockIdx.y * 32;
  int c0 = blockIdx.x * 32;
  int tx = threadIdx.x & 31, ty = threadIdx.x >> 5;
  const float* s = src + (size_t)l * R * C;
#pragma unroll
  for (int i = 0; i < 4; ++i)
    t[ty + i * 8][tx] = s[(size_t)(r0 + ty + i * 8) * C + c0 + tx];
  __syncthreads();
  bf16* d = dst + (size_t)l * layer_stride;
#pragma unroll
  for (int i = 0; i < 4; ++i) {
    int n = c0 + ty + i * 8, k = r0 + tx;
    d[(size_t)(row_off + n) * R + k] = __float2bfloat16(t[tx][ty + i * 8]);
  }
}

// dec_w [768][16] fp32 -> dwT [j][k] bf16 (rows 16..127 pre-zeroed)
__global__ void dec_transpose(const float* __restrict__ dw, bf16* __restrict__ dwT) {
  int idx = blockIdx.x * 256 + threadIdx.x;   // 16*768
  if (idx >= 12288) return;
  int k = idx % 768, j = idx / 768;
  dwT[j * 768 + k] = __float2bfloat16(dw[k * 16 + j]);
}

// ---------------- patch embed + pos embed ----------------
__global__ void patch_embed(const float* __restrict__ x, const float* __restrict__ pw,
                            const float* __restrict__ pb, const float* __restrict__ pos,
                            float* __restrict__ xs) {
  int idx = blockIdx.x * 256 + threadIdx.x;
  int d = idx % 768;
  int n = (idx / 768) & 255;
  int b = idx / (768 * 256);
  int gi = n >> 4, gj = n & 15;
  float acc = pb[d];
#pragma unroll
  for (int c = 0; c < 4; ++c)
#pragma unroll
    for (int p = 0; p < 2; ++p)
#pragma unroll
      for (int q = 0; q < 2; ++q)
        acc += x[((b * 4 + c) * 32 + gi * 2 + p) * 32 + gj * 2 + q] *
               pw[((d * 4 + c) * 2 + p) * 2 + q];
  xs[idx] = acc + pos[n * 768 + d];
}

// ---------------- time embedding ----------------
__global__ void temb_kernel(const float* __restrict__ t, float* __restrict__ emb) {
  int b = blockIdx.x;
  int i = threadIdx.x;
  float f = __expf((float)i * (-logf(10000.f) / 127.f));
  float e = t[b] * f;
  emb[b * 256 + i] = sinf(e);
  emb[b * 256 + 128 + i] = cosf(e);
}

// small [32,K]@[K,768] with 8-way k-split + shuffle reduce. MODE 0: fp32+silu, 1: bf16
template <int MODE>
__global__ void smallmm_red(const float* __restrict__ in, const float* __restrict__ w,
                            const float* __restrict__ bias, void* __restrict__ out, int K) {
  int tid = threadIdx.x;
  int s = tid & 7, o = blockIdx.x * 32 + (tid >> 3);
  int d = o % 768, b = o / 768;
  int Ks = K >> 3, k0 = s * Ks;
  const float* ir = in + b * K + k0;
  const float* wr = w + (size_t)k0 * 768 + d;
  float a = 0.f;
  for (int i = 0; i < Ks; ++i) a += ir[i] * wr[(size_t)i * 768];
  a += __shfl_xor(a, 1);
  a += __shfl_xor(a, 2);
  a += __shfl_xor(a, 4);
  if (s == 0) {
    a += bias[d];
    if (MODE == 0) {
      a = a / (1.f + __expf(-a));
      ((float*)out)[o] = a;
    } else {
      ((bf16*)out)[o] = __float2bfloat16(a);
    }
  }
}

// bias table: btab[l][h][q][k] = rpb[l][qr-kr+15][qc-kc+15][h]  (bf16)
__global__ void build_btab(const float* __restrict__ rpb, bf16* __restrict__ btab) {
  int idx = blockIdx.x * 256 + threadIdx.x;    // 12*12*256*256
  int k = idx & 255, q = (idx >> 8) & 255;
  int lh = idx >> 16;
  int h = lh % 12, l = lh / 12;
  int ih = (q >> 4) - (k >> 4) + 15;
  int iw = (q & 15) - (k & 15) + 15;
  btab[idx] = __float2bfloat16(rpb[((l * 31 + ih) * 31 + iw) * 12 + h]);
}

// ---------------- LayerNorm fp32 -> bf16 ----------------
__global__ __launch_bounds__(256) void ln_bf16_kernel(const float* __restrict__ x,
                                                      const float* __restrict__ w,
                                                      const float* __restrict__ b,
                                                      bf16* __restrict__ out) {
  int row = blockIdx.x;
  int tid = threadIdx.x;
  const float* xr = x + (size_t)row * 768;
  float v[3];
  float s = 0.f, s2 = 0.f;
#pragma unroll
  for (int i = 0; i < 3; ++i) {
    v[i] = xr[tid + i * 256];
    s += v[i];
    s2 += v[i] * v[i];
  }
#pragma unroll
  for (int off = 32; off; off >>= 1) {
    s += __shfl_down(s, off);
    s2 += __shfl_down(s2, off);
  }
  __shared__ float ps[4], ps2[4];
  int wid = tid >> 6, lane = tid & 63;
  if (lane == 0) { ps[wid] = s; ps2[wid] = s2; }
  __syncthreads();
  s = ps[0] + ps[1] + ps[2] + ps[3];
  s2 = ps2[0] + ps2[1] + ps2[2] + ps2[3];
  float m = s * (1.f / 768.f);
  float var = s2 * (1.f / 768.f) - m * m;
  float r = rsqrtf(var + 1e-6f);
#pragma unroll
  for (int i = 0; i < 3; ++i) {
    int c = tid + i * 256;
    out[(size_t)row * 768 + c] = __float2bfloat16((v[i] - m) * r * w[c] + b[c]);
  }
}

// ---------------- MFMA GEMM 128x128 + epilogues ----------------
// EPI 0: qkv (bf16 out, +bias+ttok, ldc=2304)
// EPI 1: fp32 out = acc + bias[col] + resid
// EPI 2: bf16 out = silu(acc + bias[col])
// EPI 3: ttok producer: rows<32, col->(l,s,d), fp32 out [l][s][b][d]
// EPI 4: decode: col<16, unpatchify into d_out fp32
template <int EPI>
__global__ __launch_bounds__(256) void gemm128(
    const bf16* __restrict__ A, int lda, const bf16* __restrict__ BT, int ldb, int K,
    const float* __restrict__ p0, const float* __restrict__ p1,
    const float* __restrict__ p2, const float* __restrict__ p3,
    const float* __restrict__ p4, const float* __restrict__ p5,
    const float* __restrict__ resid, float* __restrict__ outF,
    bf16* __restrict__ outB, int ldc) {
  __shared__ bf16 As[128 * 32];
  __shared__ bf16 Bs[128 * 32];
  const int tid = threadIdx.x;
  const int wid = tid >> 6, lane = tid & 63;
  const int wr = wid >> 1, wc = wid & 1;
  const int m0 = blockIdx.y * 128, n0 = blockIdx.x * 128;
  const int l16 = lane & 15, lq = lane >> 4;

  f32x4 acc[4][4];
#pragma unroll
  for (int i = 0; i < 4; ++i)
#pragma unroll
    for (int j = 0; j < 4; ++j) acc[i][j] = f32x4{0.f, 0.f, 0.f, 0.f};

  const int r2 = tid >> 2, c2 = tid & 3;
  const bf16* ga0 = A + (size_t)(m0 + r2) * lda + c2 * 8;
  const bf16* ga1 = A + (size_t)(m0 + 64 + r2) * lda + c2 * 8;
  const bf16* gb0 = BT + (size_t)(n0 + r2) * ldb + c2 * 8;
  const bf16* gb1 = BT + (size_t)(n0 + 64 + r2) * ldb + c2 * 8;
  const unsigned offw = (unsigned)__builtin_amdgcn_readfirstlane((tid & ~63) * 16);
  char* AsB = (char*)As;
  char* BsB = (char*)Bs;

  for (int k0 = 0; k0 < K; k0 += 32) {
    gld_lds16(ga0 + k0, AsB + offw);
    gld_lds16(ga1 + k0, AsB + 4096 + offw);
    gld_lds16(gb0 + k0, BsB + offw);
    gld_lds16(gb1 + k0, BsB + 4096 + offw);
    asm volatile("s_waitcnt vmcnt(0)" ::: "memory");
    __syncthreads();
    short8 af[4], bfr[4];
#pragma unroll
    for (int i = 0; i < 4; ++i) {
      int ar = wr * 64 + i * 16 + l16;
      af[i] = *(const short8*)(AsB + ar * 64 + lq * 16);
      int br = wc * 64 + i * 16 + l16;
      bfr[i] = *(const short8*)(BsB + br * 64 + lq * 16);
    }
#pragma unroll
    for (int i = 0; i < 4; ++i)
#pragma unroll
      for (int j = 0; j < 4; ++j)
        acc[i][j] = __builtin_amdgcn_mfma_f32_16x16x32_bf16(af[i], bfr[j], acc[i][j], 0, 0, 0);
    __syncthreads();
  }

#pragma unroll
  for (int i = 0; i < 4; ++i) {
#pragma unroll
    for (int j = 0; j < 4; ++j) {
#pragma unroll
      for (int r = 0; r < 4; ++r) {
        int row = m0 + wr * 64 + i * 16 + lq * 4 + r;
        int col = n0 + wc * 64 + j * 16 + l16;
        float v = acc[i][j][r];
        if constexpr (EPI == 0) {
          int s = col / 768, d = col % 768;
          int b = row >> 8;
          const float* bs = (s == 0) ? p0 : (s == 1) ? p1 : p2;
          const float* ts = (s == 0) ? p3 : (s == 1) ? p4 : p5;
          v += bs[d] + ts[b * 768 + d];
          outB[(size_t)row * ldc + col] = __float2bfloat16(v);
        } else if constexpr (EPI == 1) {
          v += p0[col] + resid[(size_t)row * ldc + col];
          outF[(size_t)row * ldc + col] = v;
        } else if constexpr (EPI == 2) {
          v += p0[col];
          v = v / (1.f + __expf(-v));
          outB[(size_t)row * ldc + col] = __float2bfloat16(v);
        } else if constexpr (EPI == 3) {
          if (row < 32) {
            int l = col / 2304;
            int r2c = col - l * 2304;
            int s = r2c / 768, d = r2c - s * 768;
            const float* bs = (s == 0) ? p0 : (s == 1) ? p1 : p2;
            v += bs[l * 768 + d];
            outF[(size_t)((l * 3 + s) * 32 + row) * 768 + d] = v;
          }
        } else {
          if (col < 16) {
            v += p0[col];
            int b = row >> 8, n = row & 255;
            int gi = n >> 4, gj = n & 15;
            int c = col >> 2, pp = (col >> 1) & 1, qq = col & 1;
            outF[((b * 4 + c) * 32 + gi * 2 + pp) * 32 + gj * 2 + qq] = v;
          }
        }
      }
    }
  }
}

// ---------------- MFMA flash-free attention (full S in regs) ----------------
// block = (b,h), 4 waves x 64 q-rows. K LDS-swizzled via pre-swizzled gld_lds source;
// V transposed+swizzled in LDS; P transposed through per-wave LDS (retired K space).
__global__ __launch_bounds__(256) void attn_mfma(const bf16* __restrict__ qkv,
                                                 const bf16* __restrict__ btab,
                                                 bf16* __restrict__ obuf) {
  __shared__ __align__(16) char lds[65536];
  const int tid = threadIdx.x;
  const int wave = tid >> 6, lane = tid & 63;
  const int l16 = lane & 15, lq = lane >> 4;
  const int b = blockIdx.x / 12, h = blockIdx.x % 12;
  const bf16* qb = qkv + (size_t)b * 256 * 2304;

  // stage K[256][64] with XOR((tok&7)<<4) content swizzle via pre-swizzled SOURCE
  const int srcd = (((tid & 7) ^ ((tid >> 3) & 7))) * 8;
  const unsigned kbase = (unsigned)__builtin_amdgcn_readfirstlane((tid & ~63) * 16);
#pragma unroll
  for (int it = 0; it < 8; ++it) {
    int tok = it * 32 + (tid >> 3);
    gld_lds16(qb + (size_t)tok * 2304 + 768 + h * 64 + srcd, lds + it * 4096 + kbase);
  }
  // stage VT[64][256] (d-major), XOR((d&7)<<4) swizzle; writes conflict-free
  {
    const short8* vrow = (const short8*)(qb + (size_t)tid * 2304 + 1536 + h * 64);
    short8 vv[8];
#pragma unroll
    for (int c = 0; c < 8; ++c) vv[c] = vrow[c];
#pragma unroll
    for (int c = 0; c < 8; ++c)
#pragma unroll
      for (int e = 0; e < 8; ++e) {
        int d = c * 8 + e;
        unsigned off = (unsigned)(32768 + d * 512 + tid * 2) ^ ((unsigned)(d & 7) << 4);
        *(short*)(lds + off) = vv[c][e];
      }
  }
  // Q fragments (direct from global)
  short8 qf[4][2];
#pragma unroll
  for (int i = 0; i < 4; ++i)
#pragma unroll
    for (int s = 0; s < 2; ++s)
      qf[i][s] = *(const short8*)(qb + (size_t)(wave * 64 + i * 16 + l16) * 2304 +
                                  h * 64 + s * 32 + lq * 8);
  asm volatile("s_waitcnt vmcnt(0)" ::: "memory");
  __syncthreads();

  const unsigned swz = ((unsigned)(l16 & 7)) << 4;
  // S = Q K^T : 128 MFMAs
  f32x4 sacc[4][16];
#pragma unroll
  for (int i = 0; i < 4; ++i)
#pragma unroll
    for (int j = 0; j < 16; ++j) sacc[i][j] = f32x4{0.f, 0.f, 0.f, 0.f};
#pragma unroll
  for (int j = 0; j < 16; ++j) {
    unsigned rb = (unsigned)(j * 16 + l16) * 128;
    short8 k0 = *(const short8*)(lds + rb + ((unsigned)(lq * 16) ^ swz));
    short8 k1 = *(const short8*)(lds + rb + ((unsigned)(64 + lq * 16) ^ swz));
#pragma unroll
    for (int i = 0; i < 4; ++i) {
      sacc[i][j] = __builtin_amdgcn_mfma_f32_16x16x32_bf16(qf[i][0], k0, sacc[i][j], 0, 0, 0);
      sacc[i][j] = __builtin_amdgcn_mfma_f32_16x16x32_bf16(qf[i][1], k1, sacc[i][j], 0, 0, 0);
    }
  }
  __syncthreads();   // all waves done with K; K space becomes per-wave P space

  // exact softmax per q-row (16-lane shfl reduce); P kept unnormalized in sacc
  const bf16* bth = btab + (size_t)h * 65536;
  float linv[4][4];
#pragma unroll
  for (int i = 0; i < 4; ++i) {
#pragma unroll
    for (int r = 0; r < 4; ++r) {
      int q = wave * 64 + i * 16 + lq * 4 + r;
      const bf16* brow = bth + q * 256 + l16;
      float sv[16];
      float mx = -1e30f;
#pragma unroll
      for (int j = 0; j < 16; ++j) {
        sv[j] = sacc[i][j][r] * 0.125f + __bfloat162float(brow[j * 16]);
        mx = fmaxf(mx, sv[j]);
      }
      mx = fmaxf(mx, __shfl_xor(mx, 1));
      mx = fmaxf(mx, __shfl_xor(mx, 2));
      mx = fmaxf(mx, __shfl_xor(mx, 4));
      mx = fmaxf(mx, __shfl_xor(mx, 8));
      float sum = 0.f;
#pragma unroll
      for (int j = 0; j < 16; ++j) {
        float p = __expf(sv[j] - mx);
        sacc[i][j][r] = p;
        sum += p;
      }
      sum += __shfl_xor(sum, 1);
      sum += __shfl_xor(sum, 2);
      sum += __shfl_xor(sum, 4);
      sum += __shfl_xor(sum, 8);
      linv[i][r] = 1.f / sum;
    }
  }

  // O = P V : 4 chunks of 64 tokens through per-wave LDS transpose
  f32x4 oacc[4][4];
#pragma unroll
  for (int i = 0; i < 4; ++i)
#pragma unroll
    for (int j = 0; j < 4; ++j) oacc[i][j] = f32x4{0.f, 0.f, 0.f, 0.f};
  char* Pw = lds + wave * 8192;
#pragma unroll
  for (int ch = 0; ch < 4; ++ch) {
#pragma unroll
    for (int i = 0; i < 4; ++i)
#pragma unroll
      for (int jj = 0; jj < 4; ++jj)
#pragma unroll
        for (int r = 0; r < 4; ++r) {
          int rowp = i * 16 + lq * 4 + r;
          unsigned off = (unsigned)(rowp * 128) +
                         (((unsigned)((jj * 16 + l16) * 2)) ^ (((unsigned)(rowp & 7)) << 4));
          *(bf16*)(Pw + off) = __float2bfloat16(sacc[i][ch * 4 + jj][r]);
        }
#pragma unroll
    for (int ks = 0; ks < 2; ++ks) {
      short8 pa[4], vb[4];
#pragma unroll
      for (int i = 0; i < 4; ++i) {
        unsigned rowp = (unsigned)(i * 16 + l16);
        pa[i] = *(const short8*)(Pw + rowp * 128 + (((unsigned)(ks * 64 + lq * 16)) ^ swz));
      }
#pragma unroll
      for (int dj = 0; dj < 4; ++dj) {
        unsigned d = (unsigned)(dj * 16 + l16);
        vb[dj] = *(const short8*)(lds + 32768 + d * 512 +
                                  (((unsigned)(ch * 128 + ks * 64 + lq * 16)) ^ swz));
      }
#pragma unroll
      for (int i = 0; i < 4; ++i)
#pragma unroll
        for (int dj = 0; dj < 4; ++dj)
          oacc[i][dj] = __builtin_amdgcn_mfma_f32_16x16x32_bf16(pa[i], vb[dj], oacc[i][dj], 0, 0, 0);
    }
  }

#pragma unroll
  for (int i = 0; i < 4; ++i)
#pragma unroll
    for (int dj = 0; dj < 4; ++dj)
#pragma unroll
      for (int r = 0; r < 4; ++r) {
        int grow = b * 256 + wave * 64 + i * 16 + lq * 4 + r;
        int gcol = h * 64 + dj * 16 + l16;
        obuf[(size_t)grow * 768 + gcol] = __float2bfloat16(oacc[i][dj][r] * linv[i][r]);
      }
}

extern "C" void kernel_launch(void* const* d_in, const int* in_sizes, int n_in,
                              void* d_out, int out_size, void* d_ws, size_t ws_size,
                              hipStream_t stream) {
  (void)in_sizes; (void)n_in; (void)out_size; (void)ws_size;
  const float* x       = (const float*)d_in[0];
  const float* t_in    = (const float*)d_in[1];
  const float* patch_w = (const float*)d_in[2];
  const float* patch_b = (const float*)d_in[3];
  const float* pos     = (const float*)d_in[4];
  const float* t_w1    = (const float*)d_in[5];
  const float* t_b1    = (const float*)d_in[6];
  const float* t_w2    = (const float*)d_in[7];
  const float* t_b2    = (const float*)d_in[8];
  const float* norm1_w = (const float*)d_in[9];
  const float* norm1_b = (const float*)d_in[10];
  const float* wqs     = (const float*)d_in[11];
  const float* bqs     = (const float*)d_in[12];
  const float* wqt     = (const float*)d_in[13];
  const float* bqt     = (const float*)d_in[14];
  const float* wks     = (const float*)d_in[15];
  const float* bks     = (const float*)d_in[16];
  const float* wkt     = (const float*)d_in[17];
  const float* bkt     = (const float*)d_in[18];
  const float* wvs     = (const float*)d_in[19];
  const float* bvs     = (const float*)d_in[20];
  const float* wvt     = (const float*)d_in[21];
  const float* bvt     = (const float*)d_in[22];
  const float* projw   = (const float*)d_in[23];
  const float* projb   = (const float*)d_in[24];
  const float* rpb     = (const float*)d_in[25];
  const float* norm2_w = (const float*)d_in[26];
  const float* norm2_b = (const float*)d_in[27];
  const float* mlp_w1  = (const float*)d_in[28];
  const float* mlp_b1  = (const float*)d_in[29];
  const float* mlp_w2  = (const float*)d_in[30];
  const float* mlp_b2  = (const float*)d_in[31];
  const float* norm_w  = (const float*)d_in[32];
  const float* norm_b  = (const float*)d_in[33];
  const float* dec_w   = (const float*)d_in[34];
  const float* dec_b   = (const float*)d_in[35];

  char* ws = (char*)d_ws;
  size_t off = 0;
  auto alloc = [&](size_t bytes) -> void* {
    void* p = ws + off;
    off += (bytes + 255) & ~(size_t)255;
    return p;
  };
  bf16* wqkvT = (bf16*)alloc(12ull * 2304 * 768 * 2);
  bf16* projT = (bf16*)alloc(12ull * 768 * 768 * 2);
  bf16* mlp1T = (bf16*)alloc(12ull * 3072 * 768 * 2);
  bf16* mlp2T = (bf16*)alloc(12ull * 768 * 3072 * 2);
  bf16* wtT   = (bf16*)alloc(12ull * 2304 * 768 * 2);
  float* xs   = (float*)alloc(8192ull * 768 * 4);
  bf16* hbuf  = (bf16*)alloc(8192ull * 768 * 2);
  bf16* qkvb  = (bf16*)alloc(8192ull * 2304 * 2);   // NOTE: hmlp aliases qkvb+obuf
  bf16* obuf  = (bf16*)alloc(8192ull * 768 * 2);
  bf16* btab  = (bf16*)alloc(12ull * 12 * 256 * 256 * 2);
  float* ttok = (float*)alloc(12ull * 3 * 32 * 768 * 4);
  bf16* xtb   = (bf16*)alloc(128ull * 768 * 2);
  bf16* dwT   = (bf16*)alloc(128ull * 768 * 2);
  float* emb  = (float*)alloc(32ull * 256 * 4);
  float* h1   = (float*)alloc(32ull * 768 * 4);
  bf16* hmlp  = qkvb;   // 8192*3072*2 == qkvb(37.7M)+obuf(12.6M), both dead by mlp1

  // zero-pad buffers
  hipMemsetAsync(xtb, 0, 128ull * 768 * 2, stream);
  hipMemsetAsync(dwT, 0, 128ull * 768 * 2, stream);

  // weight conversion
  transpose_conv<<<dim3(24, 24, 12), 256, 0, stream>>>(wqs, wqkvT, 768, 768, 0, 2304ll * 768);
  transpose_conv<<<dim3(24, 24, 12), 256, 0, stream>>>(wks, wqkvT, 768, 768, 768, 2304ll * 768);
  transpose_conv<<<dim3(24, 24, 12), 256, 0, stream>>>(wvs, wqkvT, 768, 768, 1536, 2304ll * 768);
  transpose_conv<<<dim3(24, 24, 12), 256, 0, stream>>>(projw, projT, 768, 768, 0, 768ll * 768);
  transpose_conv<<<dim3(96, 24, 12), 256, 0, stream>>>(mlp_w1, mlp1T, 768, 3072, 0, 3072ll * 768);
  transpose_conv<<<dim3(24, 96, 12), 256, 0, stream>>>(mlp_w2, mlp2T, 3072, 768, 0, 768ll * 3072);
  transpose_conv<<<dim3(24, 24, 12), 256, 0, stream>>>(wqt, wtT, 768, 768, 0, 2304ll * 768);
  transpose_conv<<<dim3(24, 24, 12), 256, 0, stream>>>(wkt, wtT, 768, 768, 768, 2304ll * 768);
  transpose_conv<<<dim3(24, 24, 12), 256, 0, stream>>>(wvt, wtT, 768, 768, 1536, 2304ll * 768);
  dec_transpose<<<48, 256, 0, stream>>>(dec_w, dwT);
  build_btab<<<36864, 256, 0, stream>>>(rpb, btab);

  // time-token chain: emb -> h1 -> xtb(bf16, padded to 128 rows) -> ttok (GEMM)
  temb_kernel<<<32, 128, 0, stream>>>(t_in, emb);
  smallmm_red<0><<<768, 256, 0, stream>>>(emb, t_w1, t_b1, h1, 256);
  smallmm_red<1><<<768, 256, 0, stream>>>(h1, t_w2, t_b2, xtb, 768);
  gemm128<3><<<dim3(216, 1), 256, 0, stream>>>(
      xtb, 768, wtT, 768, 768, bqt, bkt, bvt, nullptr, nullptr, nullptr,
      nullptr, ttok, nullptr, 0);

  patch_embed<<<24576, 256, 0, stream>>>(x, patch_w, patch_b, pos, xs);

  for (int l = 0; l < 12; ++l) {
    ln_bf16_kernel<<<8192, 256, 0, stream>>>(xs, norm1_w + l * 768, norm1_b + l * 768, hbuf);
    gemm128<0><<<dim3(18, 64), 256, 0, stream>>>(
        hbuf, 768, wqkvT + (size_t)l * 2304 * 768, 768, 768,
        bqs + l * 768, bks + l * 768, bvs + l * 768,
        ttok + (size_t)(l * 3 + 0) * 32 * 768,
        ttok + (size_t)(l * 3 + 1) * 32 * 768,
        ttok + (size_t)(l * 3 + 2) * 32 * 768,
        nullptr, nullptr, qkvb, 2304);
    attn_mfma<<<384, 256, 0, stream>>>(qkvb, btab + (size_t)l * 12 * 65536, obuf);
    gemm128<1><<<dim3(6, 64), 256, 0, stream>>>(
        obuf, 768, projT + (size_t)l * 768 * 768, 768, 768,
        projb + l * 768, nullptr, nullptr, nullptr, nullptr, nullptr,
        xs, xs, nullptr, 768);
    ln_bf16_kernel<<<8192, 256, 0, stream>>>(xs, norm2_w + l * 768, norm2_b + l * 768, hbuf);
    gemm128<2><<<dim3(24, 64), 256, 0, stream>>>(
        hbuf, 768, mlp1T + (size_t)l * 3072 * 768, 768, 768,
        mlp_b1 + l * 3072, nullptr, nullptr, nullptr, nullptr, nullptr,
        nullptr, nullptr, hmlp, 3072);
    gemm128<1><<<dim3(6, 64), 256, 0, stream>>>(
        hmlp, 3072, mlp2T + (size_t)l * 768 * 3072, 3072, 3072,
        mlp_b2 + l * 768, nullptr, nullptr, nullptr, nullptr, nullptr,
        xs, xs, nullptr, 768);
  }
  ln_bf16_kernel<<<8192, 256, 0, stream>>>(xs, norm_w, norm_b, hbuf);
  gemm128<4><<<dim3(1, 64), 256, 0, stream>>>(
      hbuf, 768, dwT, 768, 768, dec_b, nullptr, nullptr, nullptr, nullptr, nullptr,
      nullptr, (float*)d_out, nullptr, 0);
}

// Round 3
// 3181.247 us; speedup vs baseline: 2.1422x; 1.2715x over previous
//
#include <hip/hip_runtime.h>
#include <hip/hip_bf16.h>

typedef __attribute__((ext_vector_type(8))) short short8;
typedef __attribute__((ext_vector_type(4))) float f32x4;
typedef __hip_bfloat16 bf16;

#define AS1 __attribute__((address_space(1)))
#define AS3 __attribute__((address_space(3)))

__device__ __forceinline__ void gld_lds16(const void* g, void* lds) {
  __builtin_amdgcn_global_load_lds((const AS1 unsigned int*)g,
                                   (AS3 unsigned int*)lds, 16, 0, 0);
}

// ---------------- weight transpose + fp32->bf16 convert ----------------
__global__ void transpose_conv(const float* __restrict__ src, bf16* __restrict__ dst,
                               int R, int C, int row_off, long long layer_stride) {
  __shared__ float t[32][33];
  int l = blockIdx.z;
  int r0 = blockIdx.y * 32;
  int c0 = blockIdx.x * 32;
  int tx = threadIdx.x & 31, ty = threadIdx.x >> 5;
  const float* s = src + (size_t)l * R * C;
#pragma unroll
  for (int i = 0; i < 4; ++i)
    t[ty + i * 8][tx] = s[(size_t)(r0 + ty + i * 8) * C + c0 + tx];
  __syncthreads();
  bf16* d = dst + (size_t)l * layer_stride;
#pragma unroll
  for (int i = 0; i < 4; ++i) {
    int n = c0 + ty + i * 8, k = r0 + tx;
    d[(size_t)(row_off + n) * R + k] = __float2bfloat16(t[tx][ty + i * 8]);
  }
}

// dec_w [768][16] fp32 -> dwT [j][k] bf16 (rows 16..127 pre-zeroed)
__global__ void dec_transpose(const float* __restrict__ dw, bf16* __restrict__ dwT) {
  int idx = blockIdx.x * 256 + threadIdx.x;   // 16*768
  if (idx >= 12288) return;
  int k = idx % 768, j = idx / 768;
  dwT[j * 768 + k] = __float2bfloat16(dw[k * 16 + j]);
}

// ---------------- patch embed + pos embed ----------------
__global__ void patch_embed(const float* __restrict__ x, const float* __restrict__ pw,
                            const float* __restrict__ pb, const float* __restrict__ pos,
                            float* __restrict__ xs) {
  int idx = blockIdx.x * 256 + threadIdx.x;
  int d = idx % 768;
  int n = (idx / 768) & 255;
  int b = idx / (768 * 256);
  int gi = n >> 4, gj = n & 15;
  float acc = pb[d];
#pragma unroll
  for (int c = 0; c < 4; ++c)
#pragma unroll
    for (int p = 0; p < 2; ++p)
#pragma unroll
      for (int q = 0; q < 2; ++q)
        acc += x[((b * 4 + c) * 32 + gi * 2 + p) * 32 + gj * 2 + q] *
               pw[((d * 4 + c) * 2 + p) * 2 + q];
  xs[idx] = acc + pos[n * 768 + d];
}

// ---------------- time embedding ----------------
__global__ void temb_kernel(const float* __restrict__ t, float* __restrict__ emb) {
  int b = blockIdx.x;
  int i = threadIdx.x;
  float f = __expf((float)i * (-logf(10000.f) / 127.f));
  float e = t[b] * f;
  emb[b * 256 + i] = sinf(e);
  emb[b * 256 + 128 + i] = cosf(e);
}

// small [32,K]@[K,768] with 8-way k-split + shuffle reduce. MODE 0: fp32+silu, 1: bf16
template <int MODE>
__global__ void smallmm_red(const float* __restrict__ in, const float* __restrict__ w,
                            const float* __restrict__ bias, void* __restrict__ out, int K) {
  int tid = threadIdx.x;
  int s = tid & 7, o = blockIdx.x * 32 + (tid >> 3);
  int d = o % 768, b = o / 768;
  int Ks = K >> 3, k0 = s * Ks;
  const float* ir = in + b * K + k0;
  const float* wr = w + (size_t)k0 * 768 + d;
  float a = 0.f;
  for (int i = 0; i < Ks; ++i) a += ir[i] * wr[(size_t)i * 768];
  a += __shfl_xor(a, 1);
  a += __shfl_xor(a, 2);
  a += __shfl_xor(a, 4);
  if (s == 0) {
    a += bias[d];
    if (MODE == 0) {
      a = a / (1.f + __expf(-a));
      ((float*)out)[o] = a;
    } else {
      ((bf16*)out)[o] = __float2bfloat16(a);
    }
  }
}

// bias table: btab[l][h][q][k] = rpb[l][qr-kr+15][qc-kc+15][h]  (bf16)
__global__ void build_btab(const float* __restrict__ rpb, bf16* __restrict__ btab) {
  int idx = blockIdx.x * 256 + threadIdx.x;    // 12*12*256*256
  int k = idx & 255, q = (idx >> 8) & 255;
  int lh = idx >> 16;
  int h = lh % 12, l = lh / 12;
  int ih = (q >> 4) - (k >> 4) + 15;
  int iw = (q & 15) - (k & 15) + 15;
  btab[idx] = __float2bfloat16(rpb[((l * 31 + ih) * 31 + iw) * 12 + h]);
}

// ---------------- LayerNorm fp32 -> bf16 ----------------
__global__ __launch_bounds__(256) void ln_bf16_kernel(const float* __restrict__ x,
                                                      const float* __restrict__ w,
                                                      const float* __restrict__ b,
                                                      bf16* __restrict__ out) {
  int row = blockIdx.x;
  int tid = threadIdx.x;
  const float* xr = x + (size_t)row * 768;
  float v[3];
  float s = 0.f, s2 = 0.f;
#pragma unroll
  for (int i = 0; i < 3; ++i) {
    v[i] = xr[tid + i * 256];
    s += v[i];
    s2 += v[i] * v[i];
  }
#pragma unroll
  for (int off = 32; off; off >>= 1) {
    s += __shfl_down(s, off);
    s2 += __shfl_down(s2, off);
  }
  __shared__ float ps[4], ps2[4];
  int wid = tid >> 6, lane = tid & 63;
  if (lane == 0) { ps[wid] = s; ps2[wid] = s2; }
  __syncthreads();
  s = ps[0] + ps[1] + ps[2] + ps[3];
  s2 = ps2[0] + ps2[1] + ps2[2] + ps2[3];
  float m = s * (1.f / 768.f);
  float var = s2 * (1.f / 768.f) - m * m;
  float r = rsqrtf(var + 1e-6f);
#pragma unroll
  for (int i = 0; i < 3; ++i) {
    int c = tid + i * 256;
    out[(size_t)row * 768 + c] = __float2bfloat16((v[i] - m) * r * w[c] + b[c]);
  }
}

// ---------------- MFMA GEMM 128x128, BK=64, dbuf 2-phase, swizzled LDS ----------------
// EPI 0: qkv (bf16 out, +bias+ttok, ldc=2304)
// EPI 1: fp32 out = acc + bias[col] + resid
// EPI 2: bf16 out = silu(acc + bias[col])
// EPI 3: ttok producer: rows<32, col->(l,s,d), fp32 out [l][s][b][d]
// EPI 4: decode: col<16, unpatchify into d_out fp32
template <int EPI>
__global__ __launch_bounds__(256) void gemm128(
    const bf16* __restrict__ A, int lda, const bf16* __restrict__ BT, int ldb, int K,
    const float* __restrict__ p0, const float* __restrict__ p1,
    const float* __restrict__ p2, const float* __restrict__ p3,
    const float* __restrict__ p4, const float* __restrict__ p5,
    const float* __restrict__ resid, float* __restrict__ outF,
    bf16* __restrict__ outB, int ldc) {
  __shared__ __align__(16) char lds[65536];   // 2 bufs x (A 16K + B 16K)
  const int tid = threadIdx.x;
  const int wid = tid >> 6, lane = tid & 63;
  const int wr = wid >> 1, wc = wid & 1;
  // XCD-aware remap (all grids here have nwg % 8 == 0)
  const int nwg = gridDim.x * gridDim.y;
  const int bid = blockIdx.y * gridDim.x + blockIdx.x;
  const int swzb = (bid & 7) * (nwg >> 3) + (bid >> 3);
  const int m0 = (swzb / gridDim.x) * 128, n0 = (swzb % gridDim.x) * 128;
  const int l16 = lane & 15, lq = lane >> 4;

  f32x4 acc[4][4];
#pragma unroll
  for (int i = 0; i < 4; ++i)
#pragma unroll
    for (int j = 0; j < 4; ++j) acc[i][j] = f32x4{0.f, 0.f, 0.f, 0.f};

  // staging: thread -> (row = tid>>3, slot = tid&7); content swizzle slot^=(row&7)
  // applied on the GLOBAL source (linear LDS dest required by global_load_lds).
  const int arow = tid >> 3;
  const int aslot = (tid & 7) ^ (arow & 7);
  const bf16* gA = A + (size_t)(m0 + arow) * lda + aslot * 8;
  const bf16* gB = BT + (size_t)(n0 + arow) * ldb + aslot * 8;
  const unsigned offw = (unsigned)__builtin_amdgcn_readfirstlane((tid & ~63) * 16);

  const int NT = K >> 6;
  auto stage = [&](int buf, int t) {
    char* p = lds + buf * 32768;
    const int k = t * 64;
#pragma unroll
    for (int it = 0; it < 4; ++it) {
      gld_lds16(gA + (size_t)it * 32 * lda + k, p + it * 4096 + offw);
      gld_lds16(gB + (size_t)it * 32 * ldb + k, p + 16384 + it * 4096 + offw);
    }
  };

  stage(0, 0);
  const unsigned swb = ((unsigned)(l16 & 7)) << 4;  // read-side XOR (row&7)<<4
  for (int t = 0; t < NT; ++t) {
    char* cur = lds + (t & 1) * 32768;
    if (t + 1 < NT) {
      stage((t + 1) & 1, t + 1);
      asm volatile("s_waitcnt vmcnt(8)" ::: "memory");   // tile t resident; t+1 in flight
    } else {
      asm volatile("s_waitcnt vmcnt(0)" ::: "memory");
    }
    __builtin_amdgcn_s_barrier();
#pragma unroll
    for (int ks = 0; ks < 2; ++ks) {
      short8 af[4], bfr[4];
      const unsigned ko = ((unsigned)(ks * 64 + lq * 16)) ^ swb;
#pragma unroll
      for (int i = 0; i < 4; ++i) {
        af[i]  = *(const short8*)(cur + (wr * 64 + i * 16 + l16) * 128 + ko);
        bfr[i] = *(const short8*)(cur + 16384 + (wc * 64 + i * 16 + l16) * 128 + ko);
      }
#pragma unroll
      for (int i = 0; i < 4; ++i)
#pragma unroll
        for (int j = 0; j < 4; ++j)
          acc[i][j] = __builtin_amdgcn_mfma_f32_16x16x32_bf16(af[i], bfr[j], acc[i][j], 0, 0, 0);
    }
    __builtin_amdgcn_s_barrier();   // all reads of cur done before it is re-staged
  }

#pragma unroll
  for (int i = 0; i < 4; ++i) {
#pragma unroll
    for (int j = 0; j < 4; ++j) {
#pragma unroll
      for (int r = 0; r < 4; ++r) {
        int row = m0 + wr * 64 + i * 16 + lq * 4 + r;
        int col = n0 + wc * 64 + j * 16 + l16;
        float v = acc[i][j][r];
        if constexpr (EPI == 0) {
          int s = col / 768, d = col % 768;
          int b = row >> 8;
          const float* bs = (s == 0) ? p0 : (s == 1) ? p1 : p2;
          const float* ts = (s == 0) ? p3 : (s == 1) ? p4 : p5;
          v += bs[d] + ts[b * 768 + d];
          outB[(size_t)row * ldc + col] = __float2bfloat16(v);
        } else if constexpr (EPI == 1) {
          v += p0[col] + resid[(size_t)row * ldc + col];
          outF[(size_t)row * ldc + col] = v;
        } else if constexpr (EPI == 2) {
          v += p0[col];
          v = v / (1.f + __expf(-v));
          outB[(size_t)row * ldc + col] = __float2bfloat16(v);
        } else if constexpr (EPI == 3) {
          if (row < 32) {
            int l = col / 2304;
            int r2c = col - l * 2304;
            int s = r2c / 768, d = r2c - s * 768;
            const float* bs = (s == 0) ? p0 : (s == 1) ? p1 : p2;
            v += bs[l * 768 + d];
            outF[(size_t)((l * 3 + s) * 32 + row) * 768 + d] = v;
          }
        } else {
          if (col < 16) {
            v += p0[col];
            int b = row >> 8, n = row & 255;
            int gi = n >> 4, gj = n & 15;
            int c = col >> 2, pp = (col >> 1) & 1, qq = col & 1;
            outF[((b * 4 + c) * 32 + gi * 2 + pp) * 32 + gj * 2 + qq] = v;
          }
        }
      }
    }
  }
}

// ---------------- MFMA flash-free attention (full S in regs) ----------------
__global__ __launch_bounds__(256) void attn_mfma(const bf16* __restrict__ qkv,
                                                 const bf16* __restrict__ btab,
                                                 bf16* __restrict__ obuf) {
  __shared__ __align__(16) char lds[65536];
  const int tid = threadIdx.x;
  const int wave = tid >> 6, lane = tid & 63;
  const int l16 = lane & 15, lq = lane >> 4;
  const int b = blockIdx.x / 12, h = blockIdx.x % 12;
  const bf16* qb = qkv + (size_t)b * 256 * 2304;

  const int srcd = (((tid & 7) ^ ((tid >> 3) & 7))) * 8;
  const unsigned kbase = (unsigned)__builtin_amdgcn_readfirstlane((tid & ~63) * 16);
#pragma unroll
  for (int it = 0; it < 8; ++it) {
    int tok = it * 32 + (tid >> 3);
    gld_lds16(qb + (size_t)tok * 2304 + 768 + h * 64 + srcd, lds + it * 4096 + kbase);
  }
  {
    const short8* vrow = (const short8*)(qb + (size_t)tid * 2304 + 1536 + h * 64);
    short8 vv[8];
#pragma unroll
    for (int c = 0; c < 8; ++c) vv[c] = vrow[c];
#pragma unroll
    for (int c = 0; c < 8; ++c)
#pragma unroll
      for (int e = 0; e < 8; ++e) {
        int d = c * 8 + e;
        unsigned off = (unsigned)(32768 + d * 512 + tid * 2) ^ ((unsigned)(d & 7) << 4);
        *(short*)(lds + off) = vv[c][e];
      }
  }
  short8 qf[4][2];
#pragma unroll
  for (int i = 0; i < 4; ++i)
#pragma unroll
    for (int s = 0; s < 2; ++s)
      qf[i][s] = *(const short8*)(qb + (size_t)(wave * 64 + i * 16 + l16) * 2304 +
                                  h * 64 + s * 32 + lq * 8);
  asm volatile("s_waitcnt vmcnt(0)" ::: "memory");
  __syncthreads();

  const unsigned swz = ((unsigned)(l16 & 7)) << 4;
  f32x4 sacc[4][16];
#pragma unroll
  for (int i = 0; i < 4; ++i)
#pragma unroll
    for (int j = 0; j < 16; ++j) sacc[i][j] = f32x4{0.f, 0.f, 0.f, 0.f};
#pragma unroll
  for (int j = 0; j < 16; ++j) {
    unsigned rb = (unsigned)(j * 16 + l16) * 128;
    short8 k0 = *(const short8*)(lds + rb + ((unsigned)(lq * 16) ^ swz));
    short8 k1 = *(const short8*)(lds + rb + ((unsigned)(64 + lq * 16) ^ swz));
#pragma unroll
    for (int i = 0; i < 4; ++i) {
      sacc[i][j] = __builtin_amdgcn_mfma_f32_16x16x32_bf16(qf[i][0], k0, sacc[i][j], 0, 0, 0);
      sacc[i][j] = __builtin_amdgcn_mfma_f32_16x16x32_bf16(qf[i][1], k1, sacc[i][j], 0, 0, 0);
    }
  }
  __syncthreads();

  const bf16* bth = btab + (size_t)h * 65536;
  float linv[4][4];
#pragma unroll
  for (int i = 0; i < 4; ++i) {
#pragma unroll
    for (int r = 0; r < 4; ++r) {
      int q = wave * 64 + i * 16 + lq * 4 + r;
      const bf16* brow = bth + q * 256 + l16;
      float sv[16];
      float mx = -1e30f;
#pragma unroll
      for (int j = 0; j < 16; ++j) {
        sv[j] = sacc[i][j][r] * 0.125f + __bfloat162float(brow[j * 16]);
        mx = fmaxf(mx, sv[j]);
      }
      mx = fmaxf(mx, __shfl_xor(mx, 1));
      mx = fmaxf(mx, __shfl_xor(mx, 2));
      mx = fmaxf(mx, __shfl_xor(mx, 4));
      mx = fmaxf(mx, __shfl_xor(mx, 8));
      float sum = 0.f;
#pragma unroll
      for (int j = 0; j < 16; ++j) {
        float p = __expf(sv[j] - mx);
        sacc[i][j][r] = p;
        sum += p;
      }
      sum += __shfl_xor(sum, 1);
      sum += __shfl_xor(sum, 2);
      sum += __shfl_xor(sum, 4);
      sum += __shfl_xor(sum, 8);
      linv[i][r] = 1.f / sum;
    }
  }

  f32x4 oacc[4][4];
#pragma unroll
  for (int i = 0; i < 4; ++i)
#pragma unroll
    for (int j = 0; j < 4; ++j) oacc[i][j] = f32x4{0.f, 0.f, 0.f, 0.f};
  char* Pw = lds + wave * 8192;
#pragma unroll
  for (int ch = 0; ch < 4; ++ch) {
#pragma unroll
    for (int i = 0; i < 4; ++i)
#pragma unroll
      for (int jj = 0; jj < 4; ++jj)
#pragma unroll
        for (int r = 0; r < 4; ++r) {
          int rowp = i * 16 + lq * 4 + r;
          unsigned off = (unsigned)(rowp * 128) +
                         (((unsigned)((jj * 16 + l16) * 2)) ^ (((unsigned)(rowp & 7)) << 4));
          *(bf16*)(Pw + off) = __float2bfloat16(sacc[i][ch * 4 + jj][r]);
        }
#pragma unroll
    for (int ks = 0; ks < 2; ++ks) {
      short8 pa[4], vb[4];
#pragma unroll
      for (int i = 0; i < 4; ++i) {
        unsigned rowp = (unsigned)(i * 16 + l16);
        pa[i] = *(const short8*)(Pw + rowp * 128 + (((unsigned)(ks * 64 + lq * 16)) ^ swz));
      }
#pragma unroll
      for (int dj = 0; dj < 4; ++dj) {
        unsigned d = (unsigned)(dj * 16 + l16);
        vb[dj] = *(const short8*)(lds + 32768 + d * 512 +
                                  (((unsigned)(ch * 128 + ks * 64 + lq * 16)) ^ swz));
      }
#pragma unroll
      for (int i = 0; i < 4; ++i)
#pragma unroll
        for (int dj = 0; dj < 4; ++dj)
          oacc[i][dj] = __builtin_amdgcn_mfma_f32_16x16x32_bf16(pa[i], vb[dj], oacc[i][dj], 0, 0, 0);
    }
  }

#pragma unroll
  for (int i = 0; i < 4; ++i)
#pragma unroll
    for (int dj = 0; dj < 4; ++dj)
#pragma unroll
      for (int r = 0; r < 4; ++r) {
        int grow = b * 256 + wave * 64 + i * 16 + lq * 4 + r;
        int gcol = h * 64 + dj * 16 + l16;
        obuf[(size_t)grow * 768 + gcol] = __float2bfloat16(oacc[i][dj][r] * linv[i][r]);
      }
}

extern "C" void kernel_launch(void* const* d_in, const int* in_sizes, int n_in,
                              void* d_out, int out_size, void* d_ws, size_t ws_size,
                              hipStream_t stream) {
  (void)in_sizes; (void)n_in; (void)out_size; (void)ws_size;
  const float* x       = (const float*)d_in[0];
  const float* t_in    = (const float*)d_in[1];
  const float* patch_w = (const float*)d_in[2];
  const float* patch_b = (const float*)d_in[3];
  const float* pos     = (const float*)d_in[4];
  const float* t_w1    = (const float*)d_in[5];
  const float* t_b1    = (const float*)d_in[6];
  const float* t_w2    = (const float*)d_in[7];
  const float* t_b2    = (const float*)d_in[8];
  const float* norm1_w = (const float*)d_in[9];
  const float* norm1_b = (const float*)d_in[10];
  const float* wqs     = (const float*)d_in[11];
  const float* bqs     = (const float*)d_in[12];
  const float* wqt     = (const float*)d_in[13];
  const float* bqt     = (const float*)d_in[14];
  const float* wks     = (const float*)d_in[15];
  const float* bks     = (const float*)d_in[16];
  const float* wkt     = (const float*)d_in[17];
  const float* bkt     = (const float*)d_in[18];
  const float* wvs     = (const float*)d_in[19];
  const float* bvs     = (const float*)d_in[20];
  const float* wvt     = (const float*)d_in[21];
  const float* bvt     = (const float*)d_in[22];
  const float* projw   = (const float*)d_in[23];
  const float* projb   = (const float*)d_in[24];
  const float* rpb     = (const float*)d_in[25];
  const float* norm2_w = (const float*)d_in[26];
  const float* norm2_b = (const float*)d_in[27];
  const float* mlp_w1  = (const float*)d_in[28];
  const float* mlp_b1  = (const float*)d_in[29];
  const float* mlp_w2  = (const float*)d_in[30];
  const float* mlp_b2  = (const float*)d_in[31];
  const float* norm_w  = (const float*)d_in[32];
  const float* norm_b  = (const float*)d_in[33];
  const float* dec_w   = (const float*)d_in[34];
  const float* dec_b   = (const float*)d_in[35];

  char* ws = (char*)d_ws;
  size_t off = 0;
  auto alloc = [&](size_t bytes) -> void* {
    void* p = ws + off;
    off += (bytes + 255) & ~(size_t)255;
    return p;
  };
  bf16* wqkvT = (bf16*)alloc(12ull * 2304 * 768 * 2);
  bf16* projT = (bf16*)alloc(12ull * 768 * 768 * 2);
  bf16* mlp1T = (bf16*)alloc(12ull * 3072 * 768 * 2);
  bf16* mlp2T = (bf16*)alloc(12ull * 768 * 3072 * 2);
  bf16* wtT   = (bf16*)alloc(12ull * 2304 * 768 * 2);
  float* xs   = (float*)alloc(8192ull * 768 * 4);
  bf16* hbuf  = (bf16*)alloc(8192ull * 768 * 2);
  bf16* qkvb  = (bf16*)alloc(8192ull * 2304 * 2);
  bf16* obuf  = (bf16*)alloc(8192ull * 768 * 2);
  bf16* btab  = (bf16*)alloc(12ull * 12 * 256 * 256 * 2);
  float* ttok = (float*)alloc(12ull * 3 * 32 * 768 * 4);
  bf16* xtb   = (bf16*)alloc(128ull * 768 * 2);
  bf16* dwT   = (bf16*)alloc(128ull * 768 * 2);
  float* emb  = (float*)alloc(32ull * 256 * 4);
  float* h1   = (float*)alloc(32ull * 768 * 4);
  bf16* hmlp  = qkvb;   // 8192*3072*2 fits in qkvb+obuf, both dead by mlp1

  hipMemsetAsync(xtb, 0, 128ull * 768 * 2, stream);
  hipMemsetAsync(dwT, 0, 128ull * 768 * 2, stream);

  transpose_conv<<<dim3(24, 24, 12), 256, 0, stream>>>(wqs, wqkvT, 768, 768, 0, 2304ll * 768);
  transpose_conv<<<dim3(24, 24, 12), 256, 0, stream>>>(wks, wqkvT, 768, 768, 768, 2304ll * 768);
  transpose_conv<<<dim3(24, 24, 12), 256, 0, stream>>>(wvs, wqkvT, 768, 768, 1536, 2304ll * 768);
  transpose_conv<<<dim3(24, 24, 12), 256, 0, stream>>>(projw, projT, 768, 768, 0, 768ll * 768);
  transpose_conv<<<dim3(96, 24, 12), 256, 0, stream>>>(mlp_w1, mlp1T, 768, 3072, 0, 3072ll * 768);
  transpose_conv<<<dim3(24, 96, 12), 256, 0, stream>>>(mlp_w2, mlp2T, 3072, 768, 0, 768ll * 3072);
  transpose_conv<<<dim3(24, 24, 12), 256, 0, stream>>>(wqt, wtT, 768, 768, 0, 2304ll * 768);
  transpose_conv<<<dim3(24, 24, 12), 256, 0, stream>>>(wkt, wtT, 768, 768, 768, 2304ll * 768);
  transpose_conv<<<dim3(24, 24, 12), 256, 0, stream>>>(wvt, wtT, 768, 768, 1536, 2304ll * 768);
  dec_transpose<<<48, 256, 0, stream>>>(dec_w, dwT);
  build_btab<<<36864, 256, 0, stream>>>(rpb, btab);

  temb_kernel<<<32, 128, 0, stream>>>(t_in, emb);
  smallmm_red<0><<<768, 256, 0, stream>>>(emb, t_w1, t_b1, h1, 256);
  smallmm_red<1><<<768, 256, 0, stream>>>(h1, t_w2, t_b2, xtb, 768);
  gemm128<3><<<dim3(216, 1), 256, 0, stream>>>(
      xtb, 768, wtT, 768, 768, bqt, bkt, bvt, nullptr, nullptr, nullptr,
      nullptr, ttok, nullptr, 0);

  patch_embed<<<24576, 256, 0, stream>>>(x, patch_w, patch_b, pos, xs);

  for (int l = 0; l < 12; ++l) {
    ln_bf16_kernel<<<8192, 256, 0, stream>>>(xs, norm1_w + l * 768, norm1_b + l * 768, hbuf);
    gemm128<0><<<dim3(18, 64), 256, 0, stream>>>(
        hbuf, 768, wqkvT + (size_t)l * 2304 * 768, 768, 768,
        bqs + l * 768, bks + l * 768, bvs + l * 768,
        ttok + (size_t)(l * 3 + 0) * 32 * 768,
        ttok + (size_t)(l * 3 + 1) * 32 * 768,
        ttok + (size_t)(l * 3 + 2) * 32 * 768,
        nullptr, nullptr, qkvb, 2304);
    attn_mfma<<<384, 256, 0, stream>>>(qkvb, btab + (size_t)l * 12 * 65536, obuf);
    gemm128<1><<<dim3(6, 64), 256, 0, stream>>>(
        obuf, 768, projT + (size_t)l * 768 * 768, 768, 768,
        projb + l * 768, nullptr, nullptr, nullptr, nullptr, nullptr,
        xs, xs, nullptr, 768);
    ln_bf16_kernel<<<8192, 256, 0, stream>>>(xs, norm2_w + l * 768, norm2_b + l * 768, hbuf);
    gemm128<2><<<dim3(24, 64), 256, 0, stream>>>(
        hbuf, 768, mlp1T + (size_t)l * 3072 * 768, 768, 768,
        mlp_b1 + l * 3072, nullptr, nullptr, nullptr, nullptr, nullptr,
        nullptr, nullptr, hmlp, 3072);
    gemm128<1><<<dim3(6, 64), 256, 0, stream>>>(
        hmlp, 3072, mlp2T + (size_t)l * 768 * 3072, 3072, 3072,
        mlp_b2 + l * 768, nullptr, nullptr, nullptr, nullptr, nullptr,
        xs, xs, nullptr, 768);
  }
  ln_bf16_kernel<<<8192, 256, 0, stream>>>(xs, norm_w, norm_b, hbuf);
  gemm128<4><<<dim3(1, 64), 256, 0, stream>>>(
      hbuf, 768, dwT, 768, 768, dec_b, nullptr, nullptr, nullptr, nullptr, nullptr,
      nullptr, (float*)d_out, nullptr, 0);
}

// Round 4
// 2841.422 us; speedup vs baseline: 2.3984x; 1.1196x over previous
//
#include <hip/hip_runtime.h>
#include <hip/hip_bf16.h>

typedef __attribute__((ext_vector_type(8))) short short8;
typedef __attribute__((ext_vector_type(4))) short s16x4;
typedef __attribute__((ext_vector_type(4))) float f32x4;
typedef __hip_bfloat16 bf16;

#define AS1 __attribute__((address_space(1)))
#define AS3 __attribute__((address_space(3)))

__device__ __forceinline__ float b2f(short u) {
  union { unsigned int i; float f; } x;
  x.i = ((unsigned int)(unsigned short)u) << 16;
  return x.f;
}
__device__ __forceinline__ short f2bs(float f) {
  bf16 t = __float2bfloat16(f);
  return *reinterpret_cast<short*>(&t);
}

__device__ __forceinline__ void gld_lds16(const void* g, void* lds) {
  __builtin_amdgcn_global_load_lds((const AS1 unsigned int*)g,
                                   (AS3 unsigned int*)lds, 16, 0, 0);
}

// ---------------- weight transpose + fp32->bf16 convert ----------------
__global__ void transpose_conv(const float* __restrict__ src, bf16* __restrict__ dst,
                               int R, int C, int row_off, long long layer_stride) {
  __shared__ float t[32][33];
  int l = blockIdx.z;
  int r0 = blockIdx.y * 32;
  int c0 = blockIdx.x * 32;
  int tx = threadIdx.x & 31, ty = threadIdx.x >> 5;
  const float* s = src + (size_t)l * R * C;
#pragma unroll
  for (int i = 0; i < 4; ++i)
    t[ty + i * 8][tx] = s[(size_t)(r0 + ty + i * 8) * C + c0 + tx];
  __syncthreads();
  bf16* d = dst + (size_t)l * layer_stride;
#pragma unroll
  for (int i = 0; i < 4; ++i) {
    int n = c0 + ty + i * 8, k = r0 + tx;
    d[(size_t)(row_off + n) * R + k] = __float2bfloat16(t[tx][ty + i * 8]);
  }
}

// dec_w [768][16] fp32 -> dwT [j][k] bf16 (rows 16..127 pre-zeroed)
__global__ void dec_transpose(const float* __restrict__ dw, bf16* __restrict__ dwT) {
  int idx = blockIdx.x * 256 + threadIdx.x;   // 16*768
  if (idx >= 12288) return;
  int k = idx % 768, j = idx / 768;
  dwT[j * 768 + k] = __float2bfloat16(dw[k * 16 + j]);
}

// ---------------- patch embed + pos embed ----------------
__global__ void patch_embed(const float* __restrict__ x, const float* __restrict__ pw,
                            const float* __restrict__ pb, const float* __restrict__ pos,
                            float* __restrict__ xs) {
  int idx = blockIdx.x * 256 + threadIdx.x;
  int d = idx % 768;
  int n = (idx / 768) & 255;
  int b = idx / (768 * 256);
  int gi = n >> 4, gj = n & 15;
  float acc = pb[d];
#pragma unroll
  for (int c = 0; c < 4; ++c)
#pragma unroll
    for (int p = 0; p < 2; ++p)
#pragma unroll
      for (int q = 0; q < 2; ++q)
        acc += x[((b * 4 + c) * 32 + gi * 2 + p) * 32 + gj * 2 + q] *
               pw[((d * 4 + c) * 2 + p) * 2 + q];
  xs[idx] = acc + pos[n * 768 + d];
}

// ---------------- time embedding ----------------
__global__ void temb_kernel(const float* __restrict__ t, float* __restrict__ emb) {
  int b = blockIdx.x;
  int i = threadIdx.x;
  float f = __expf((float)i * (-logf(10000.f) / 127.f));
  float e = t[b] * f;
  emb[b * 256 + i] = sinf(e);
  emb[b * 256 + 128 + i] = cosf(e);
}

// small [32,K]@[K,768] with 8-way k-split + shuffle reduce. MODE 0: fp32+silu, 1: bf16
template <int MODE>
__global__ void smallmm_red(const float* __restrict__ in, const float* __restrict__ w,
                            const float* __restrict__ bias, void* __restrict__ out, int K) {
  int tid = threadIdx.x;
  int s = tid & 7, o = blockIdx.x * 32 + (tid >> 3);
  int d = o % 768, b = o / 768;
  int Ks = K >> 3, k0 = s * Ks;
  const float* ir = in + b * K + k0;
  const float* wr = w + (size_t)k0 * 768 + d;
  float a = 0.f;
  for (int i = 0; i < Ks; ++i) a += ir[i] * wr[(size_t)i * 768];
  a += __shfl_xor(a, 1);
  a += __shfl_xor(a, 2);
  a += __shfl_xor(a, 4);
  if (s == 0) {
    a += bias[d];
    if (MODE == 0) {
      a = a / (1.f + __expf(-a));
      ((float*)out)[o] = a;
    } else {
      ((bf16*)out)[o] = __float2bfloat16(a);
    }
  }
}

// bias table in MFMA D-fragment order, pre-scaled by 8:
// per (l,h): idx = ((((hc*2+jb)*4 + w)*4 + i)*64 + lane)*4 + r
// q = w*64 + i*16 + (lane&15); k = hc*32 + jb*16 + (lane>>4)*4 + r
__global__ void build_btab_frag(const float* __restrict__ rpb, bf16* __restrict__ btf) {
  int idx = blockIdx.x * 256 + threadIdx.x;    // 12*12*65536
  int t = idx & 65535;
  int lh = idx >> 16;
  int h = lh % 12, l = lh / 12;
  int r = t & 3; t >>= 2;
  int lane = t & 63; t >>= 6;
  int i = t & 3; t >>= 2;
  int w = t & 3; t >>= 2;
  int jb = t & 1; t >>= 1;
  int hc = t & 7;
  int q = w * 64 + i * 16 + (lane & 15);
  int k = hc * 32 + jb * 16 + (lane >> 4) * 4 + r;
  int ih = (q >> 4) - (k >> 4) + 15;
  int iw = (q & 15) - (k & 15) + 15;
  btf[idx] = __float2bfloat16(8.0f * rpb[((l * 31 + ih) * 31 + iw) * 12 + h]);
}

// ---------------- LayerNorm fp32 -> bf16 ----------------
__global__ __launch_bounds__(256) void ln_bf16_kernel(const float* __restrict__ x,
                                                      const float* __restrict__ w,
                                                      const float* __restrict__ b,
                                                      bf16* __restrict__ out) {
  int row = blockIdx.x;
  int tid = threadIdx.x;
  const float* xr = x + (size_t)row * 768;
  float v[3];
  float s = 0.f, s2 = 0.f;
#pragma unroll
  for (int i = 0; i < 3; ++i) {
    v[i] = xr[tid + i * 256];
    s += v[i];
    s2 += v[i] * v[i];
  }
#pragma unroll
  for (int off = 32; off; off >>= 1) {
    s += __shfl_down(s, off);
    s2 += __shfl_down(s2, off);
  }
  __shared__ float ps[4], ps2[4];
  int wid = tid >> 6, lane = tid & 63;
  if (lane == 0) { ps[wid] = s; ps2[wid] = s2; }
  __syncthreads();
  s = ps[0] + ps[1] + ps[2] + ps[3];
  s2 = ps2[0] + ps2[1] + ps2[2] + ps2[3];
  float m = s * (1.f / 768.f);
  float var = s2 * (1.f / 768.f) - m * m;
  float r = rsqrtf(var + 1e-6f);
#pragma unroll
  for (int i = 0; i < 3; ++i) {
    int c = tid + i * 256;
    out[(size_t)row * 768 + c] = __float2bfloat16((v[i] - m) * r * w[c] + b[c]);
  }
}

// ---------------- MFMA GEMM 128x128, BK=64, dbuf 2-phase, swizzled LDS ----------------
template <int EPI>
__global__ __launch_bounds__(256) void gemm128(
    const bf16* __restrict__ A, int lda, const bf16* __restrict__ BT, int ldb, int K,
    const float* __restrict__ p0, const float* __restrict__ p1,
    const float* __restrict__ p2, const float* __restrict__ p3,
    const float* __restrict__ p4, const float* __restrict__ p5,
    const float* __restrict__ resid, float* __restrict__ outF,
    bf16* __restrict__ outB, int ldc) {
  __shared__ __align__(16) char lds[65536];   // 2 bufs x (A 16K + B 16K)
  const int tid = threadIdx.x;
  const int wid = tid >> 6, lane = tid & 63;
  const int wr = wid >> 1, wc = wid & 1;
  const int nwg = gridDim.x * gridDim.y;
  const int bid = blockIdx.y * gridDim.x + blockIdx.x;
  const int swzb = (bid & 7) * (nwg >> 3) + (bid >> 3);
  const int m0 = (swzb / gridDim.x) * 128, n0 = (swzb % gridDim.x) * 128;
  const int l16 = lane & 15, lq = lane >> 4;

  f32x4 acc[4][4];
#pragma unroll
  for (int i = 0; i < 4; ++i)
#pragma unroll
    for (int j = 0; j < 4; ++j) acc[i][j] = f32x4{0.f, 0.f, 0.f, 0.f};

  const int arow = tid >> 3;
  const int aslot = (tid & 7) ^ (arow & 7);
  const bf16* gA = A + (size_t)(m0 + arow) * lda + aslot * 8;
  const bf16* gB = BT + (size_t)(n0 + arow) * ldb + aslot * 8;
  const unsigned offw = (unsigned)__builtin_amdgcn_readfirstlane((tid & ~63) * 16);

  const int NT = K >> 6;
  auto stage = [&](int buf, int t) {
    char* p = lds + buf * 32768;
    const int k = t * 64;
#pragma unroll
    for (int it = 0; it < 4; ++it) {
      gld_lds16(gA + (size_t)it * 32 * lda + k, p + it * 4096 + offw);
      gld_lds16(gB + (size_t)it * 32 * ldb + k, p + 16384 + it * 4096 + offw);
    }
  };

  stage(0, 0);
  const unsigned swb = ((unsigned)(l16 & 7)) << 4;
  for (int t = 0; t < NT; ++t) {
    char* cur = lds + (t & 1) * 32768;
    if (t + 1 < NT) {
      stage((t + 1) & 1, t + 1);
      asm volatile("s_waitcnt vmcnt(8)" ::: "memory");
    } else {
      asm volatile("s_waitcnt vmcnt(0)" ::: "memory");
    }
    __builtin_amdgcn_s_barrier();
#pragma unroll
    for (int ks = 0; ks < 2; ++ks) {
      short8 af[4], bfr[4];
      const unsigned ko = ((unsigned)(ks * 64 + lq * 16)) ^ swb;
#pragma unroll
      for (int i = 0; i < 4; ++i) {
        af[i]  = *(const short8*)(cur + (wr * 64 + i * 16 + l16) * 128 + ko);
        bfr[i] = *(const short8*)(cur + 16384 + (wc * 64 + i * 16 + l16) * 128 + ko);
      }
#pragma unroll
      for (int i = 0; i < 4; ++i)
#pragma unroll
        for (int j = 0; j < 4; ++j)
          acc[i][j] = __builtin_amdgcn_mfma_f32_16x16x32_bf16(af[i], bfr[j], acc[i][j], 0, 0, 0);
    }
    __builtin_amdgcn_s_barrier();
  }

#pragma unroll
  for (int i = 0; i < 4; ++i) {
#pragma unroll
    for (int j = 0; j < 4; ++j) {
#pragma unroll
      for (int r = 0; r < 4; ++r) {
        int row = m0 + wr * 64 + i * 16 + lq * 4 + r;
        int col = n0 + wc * 64 + j * 16 + l16;
        float v = acc[i][j][r];
        if constexpr (EPI == 0) {
          int s = col / 768, d = col % 768;
          int b = row >> 8;
          const float* bs = (s == 0) ? p0 : (s == 1) ? p1 : p2;
          const float* ts = (s == 0) ? p3 : (s == 1) ? p4 : p5;
          v += bs[d] + ts[b * 768 + d];
          outB[(size_t)row * ldc + col] = __float2bfloat16(v);
        } else if constexpr (EPI == 1) {
          v += p0[col] + resid[(size_t)row * ldc + col];
          outF[(size_t)row * ldc + col] = v;
        } else if constexpr (EPI == 2) {
          v += p0[col];
          v = v / (1.f + __expf(-v));
          outB[(size_t)row * ldc + col] = __float2bfloat16(v);
        } else if constexpr (EPI == 3) {
          if (row < 32) {
            int l = col / 2304;
            int r2c = col - l * 2304;
            int s = r2c / 768, d = r2c - s * 768;
            const float* bs = (s == 0) ? p0 : (s == 1) ? p1 : p2;
            v += bs[l * 768 + d];
            outF[(size_t)((l * 3 + s) * 32 + row) * 768 + d] = v;
          }
        } else {
          if (col < 16) {
            v += p0[col];
            int b = row >> 8, n = row & 255;
            int gi = n >> 4, gj = n & 15;
            int c = col >> 2, pp = (col >> 1) & 1, qq = col & 1;
            outF[((b * 4 + c) * 32 + gi * 2 + pp) * 32 + gj * 2 + qq] = v;
          }
        }
      }
    }
  }
}

// ---------------- MFMA attention v2: transposed-S, chunked, max-free softmax ----
// block=(b,h), 4 waves x 64 q. LDS: VT 32KB @0 | P dbuf 2x16KB @32768 (64KB total).
// S^T = mfma(K,Q) per 32-tok chunk -> lane holds P for q=l16 -> vectorized P via LDS.
// K A-frags read straight from global (L2-hot). Bias pre-packed in frag order (x8).
__global__ __launch_bounds__(256) void attn_mfma(const bf16* __restrict__ qkv,
                                                 const bf16* __restrict__ btf,
                                                 bf16* __restrict__ obuf) {
  __shared__ __align__(16) char lds[65536];
  const int tid = threadIdx.x;
  const int wave = tid >> 6, lane = tid & 63;
  const int l16 = lane & 15, lq = lane >> 4;
  const int b = blockIdx.x / 12, h = blockIdx.x % 12;
  const bf16* qb = qkv + (size_t)b * 256 * 2304;

  // stage VT[64 d][256 tok], XOR ((d&7)<<4) on 16B slots; thread tid = token tid
  {
    const short8* vrow = (const short8*)(qb + (size_t)tid * 2304 + 1536 + h * 64);
    short8 vv[8];
#pragma unroll
    for (int c = 0; c < 8; ++c) vv[c] = vrow[c];
#pragma unroll
    for (int c = 0; c < 8; ++c)
#pragma unroll
      for (int e = 0; e < 8; ++e) {
        int d = c * 8 + e;
        unsigned off = (unsigned)(d * 512 + tid * 2) ^ ((unsigned)(d & 7) << 4);
        *(short*)(lds + off) = vv[c][e];
      }
  }
  // Q B-frags (q = wave*64 + i*16 + l16)
  short8 qf[4][2];
#pragma unroll
  for (int i = 0; i < 4; ++i)
#pragma unroll
    for (int ks = 0; ks < 2; ++ks)
      qf[i][ks] = *(const short8*)(qb + (size_t)(wave * 64 + i * 16 + l16) * 2304 +
                                   h * 64 + ks * 32 + lq * 8);
  __syncthreads();

  f32x4 oacc[4][4];
#pragma unroll
  for (int i = 0; i < 4; ++i)
#pragma unroll
    for (int j = 0; j < 4; ++j) oacc[i][j] = f32x4{0.f, 0.f, 0.f, 0.f};
  float lp[4] = {0.f, 0.f, 0.f, 0.f};
  const bf16* bl = btf + (size_t)h * 65536 + lane * 4;
  const unsigned swzv = ((unsigned)(l16 & 7)) << 4;
  const unsigned swzp = ((unsigned)(l16 & 3)) << 4;

  for (int hc = 0; hc < 8; ++hc) {
    // K A-frags from global (tok = hc*32 + jb*16 + l16)
    short8 kf[2][2];
#pragma unroll
    for (int jb = 0; jb < 2; ++jb) {
      const bf16* kr = qb + (size_t)(hc * 32 + jb * 16 + l16) * 2304 + 768 + h * 64 + lq * 8;
      kf[jb][0] = *(const short8*)(kr);
      kf[jb][1] = *(const short8*)(kr + 32);
    }
    // bias-init (pre-scaled x8): sacc = 8*bias; after QK: s = sacc*0.125
    f32x4 sacc[4][2];
#pragma unroll
    for (int i = 0; i < 4; ++i)
#pragma unroll
      for (int jb = 0; jb < 2; ++jb) {
        s16x4 bv = *(const s16x4*)(bl + ((size_t)((hc * 2 + jb) * 16 + wave * 4 + i) << 8));
        sacc[i][jb] = f32x4{b2f(bv[0]), b2f(bv[1]), b2f(bv[2]), b2f(bv[3])};
      }
    // S^T = K Q^T : D[tok][q]
#pragma unroll
    for (int jb = 0; jb < 2; ++jb)
#pragma unroll
      for (int i = 0; i < 4; ++i) {
        sacc[i][jb] = __builtin_amdgcn_mfma_f32_16x16x32_bf16(kf[jb][0], qf[i][0], sacc[i][jb], 0, 0, 0);
        sacc[i][jb] = __builtin_amdgcn_mfma_f32_16x16x32_bf16(kf[jb][1], qf[i][1], sacc[i][jb], 0, 0, 0);
      }
    // max-free softmax partials + pack P (bf16x4 per lane) into per-wave LDS
    char* Pw = lds + 32768 + (hc & 1) * 16384 + wave * 4096;
#pragma unroll
    for (int i = 0; i < 4; ++i)
#pragma unroll
      for (int jb = 0; jb < 2; ++jb) {
        float p0 = __expf(sacc[i][jb][0] * 0.125f);
        float p1 = __expf(sacc[i][jb][1] * 0.125f);
        float p2 = __expf(sacc[i][jb][2] * 0.125f);
        float p3 = __expf(sacc[i][jb][3] * 0.125f);
        lp[i] += (p0 + p1) + (p2 + p3);
        s16x4 pk = {f2bs(p0), f2bs(p1), f2bs(p2), f2bs(p3)};
        *(s16x4*)(Pw + (i * 16 + l16) * 64 + (((unsigned)(jb * 32 + lq * 8)) ^ swzp)) = pk;
      }
    asm volatile("s_waitcnt lgkmcnt(0)" ::: "memory");
    __builtin_amdgcn_sched_barrier(0);
    // P A-frags + V B-frags, PV accumulate
    short8 pa[4], vb[4];
#pragma unroll
    for (int i = 0; i < 4; ++i)
      pa[i] = *(const short8*)(Pw + (i * 16 + l16) * 64 + (((unsigned)(lq * 16)) ^ swzp));
#pragma unroll
    for (int dj = 0; dj < 4; ++dj)
      vb[dj] = *(const short8*)(lds + (dj * 16 + l16) * 512 +
                                (((unsigned)(hc * 64 + lq * 16)) ^ swzv));
#pragma unroll
    for (int i = 0; i < 4; ++i)
#pragma unroll
      for (int dj = 0; dj < 4; ++dj)
        oacc[i][dj] = __builtin_amdgcn_mfma_f32_16x16x32_bf16(pa[i], vb[dj], oacc[i][dj], 0, 0, 0);
  }

  // final l-reduction + normalized O write
#pragma unroll
  for (int i = 0; i < 4; ++i) {
    float l = lp[i];
    l += __shfl_xor(l, 16);
    l += __shfl_xor(l, 32);
#pragma unroll
    for (int r = 0; r < 4; ++r) {
      float linv = 1.f / __shfl(l, lq * 4 + r);
      int grow = b * 256 + wave * 64 + i * 16 + lq * 4 + r;
#pragma unroll
      for (int dj = 0; dj < 4; ++dj)
        obuf[(size_t)grow * 768 + h * 64 + dj * 16 + l16] =
            __float2bfloat16(oacc[i][dj][r] * linv);
    }
  }
}

extern "C" void kernel_launch(void* const* d_in, const int* in_sizes, int n_in,
                              void* d_out, int out_size, void* d_ws, size_t ws_size,
                              hipStream_t stream) {
  (void)in_sizes; (void)n_in; (void)out_size; (void)ws_size;
  const float* x       = (const float*)d_in[0];
  const float* t_in    = (const float*)d_in[1];
  const float* patch_w = (const float*)d_in[2];
  const float* patch_b = (const float*)d_in[3];
  const float* pos     = (const float*)d_in[4];
  const float* t_w1    = (const float*)d_in[5];
  const float* t_b1    = (const float*)d_in[6];
  const float* t_w2    = (const float*)d_in[7];
  const float* t_b2    = (const float*)d_in[8];
  const float* norm1_w = (const float*)d_in[9];
  const float* norm1_b = (const float*)d_in[10];
  const float* wqs     = (const float*)d_in[11];
  const float* bqs     = (const float*)d_in[12];
  const float* wqt     = (const float*)d_in[13];
  const float* bqt     = (const float*)d_in[14];
  const float* wks     = (const float*)d_in[15];
  const float* bks     = (const float*)d_in[16];
  const float* wkt     = (const float*)d_in[17];
  const float* bkt     = (const float*)d_in[18];
  const float* wvs     = (const float*)d_in[19];
  const float* bvs     = (const float*)d_in[20];
  const float* wvt     = (const float*)d_in[21];
  const float* bvt     = (const float*)d_in[22];
  const float* projw   = (const float*)d_in[23];
  const float* projb   = (const float*)d_in[24];
  const float* rpb     = (const float*)d_in[25];
  const float* norm2_w = (const float*)d_in[26];
  const float* norm2_b = (const float*)d_in[27];
  const float* mlp_w1  = (const float*)d_in[28];
  const float* mlp_b1  = (const float*)d_in[29];
  const float* mlp_w2  = (const float*)d_in[30];
  const float* mlp_b2  = (const float*)d_in[31];
  const float* norm_w  = (const float*)d_in[32];
  const float* norm_b  = (const float*)d_in[33];
  const float* dec_w   = (const float*)d_in[34];
  const float* dec_b   = (const float*)d_in[35];

  char* ws = (char*)d_ws;
  size_t off = 0;
  auto alloc = [&](size_t bytes) -> void* {
    void* p = ws + off;
    off += (bytes + 255) & ~(size_t)255;
    return p;
  };
  bf16* wqkvT = (bf16*)alloc(12ull * 2304 * 768 * 2);
  bf16* projT = (bf16*)alloc(12ull * 768 * 768 * 2);
  bf16* mlp1T = (bf16*)alloc(12ull * 3072 * 768 * 2);
  bf16* mlp2T = (bf16*)alloc(12ull * 768 * 3072 * 2);
  bf16* wtT   = (bf16*)alloc(12ull * 2304 * 768 * 2);
  float* xs   = (float*)alloc(8192ull * 768 * 4);
  bf16* hbuf  = (bf16*)alloc(8192ull * 768 * 2);
  bf16* qkvb  = (bf16*)alloc(8192ull * 2304 * 2);
  bf16* obuf  = (bf16*)alloc(8192ull * 768 * 2);
  bf16* btabf = (bf16*)alloc(12ull * 12 * 256 * 256 * 2);
  float* ttok = (float*)alloc(12ull * 3 * 32 * 768 * 4);
  bf16* xtb   = (bf16*)alloc(128ull * 768 * 2);
  bf16* dwT   = (bf16*)alloc(128ull * 768 * 2);
  float* emb  = (float*)alloc(32ull * 256 * 4);
  float* h1   = (float*)alloc(32ull * 768 * 4);
  bf16* hmlp  = qkvb;   // 8192*3072*2 fits in qkvb+obuf, both dead by mlp1

  hipMemsetAsync(xtb, 0, 128ull * 768 * 2, stream);
  hipMemsetAsync(dwT, 0, 128ull * 768 * 2, stream);

  transpose_conv<<<dim3(24, 24, 12), 256, 0, stream>>>(wqs, wqkvT, 768, 768, 0, 2304ll * 768);
  transpose_conv<<<dim3(24, 24, 12), 256, 0, stream>>>(wks, wqkvT, 768, 768, 768, 2304ll * 768);
  transpose_conv<<<dim3(24, 24, 12), 256, 0, stream>>>(wvs, wqkvT, 768, 768, 1536, 2304ll * 768);
  transpose_conv<<<dim3(24, 24, 12), 256, 0, stream>>>(projw, projT, 768, 768, 0, 768ll * 768);
  transpose_conv<<<dim3(96, 24, 12), 256, 0, stream>>>(mlp_w1, mlp1T, 768, 3072, 0, 3072ll * 768);
  transpose_conv<<<dim3(24, 96, 12), 256, 0, stream>>>(mlp_w2, mlp2T, 3072, 768, 0, 768ll * 3072);
  transpose_conv<<<dim3(24, 24, 12), 256, 0, stream>>>(wqt, wtT, 768, 768, 0, 2304ll * 768);
  transpose_conv<<<dim3(24, 24, 12), 256, 0, stream>>>(wkt, wtT, 768, 768, 768, 2304ll * 768);
  transpose_conv<<<dim3(24, 24, 12), 256, 0, stream>>>(wvt, wtT, 768, 768, 1536, 2304ll * 768);
  dec_transpose<<<48, 256, 0, stream>>>(dec_w, dwT);
  build_btab_frag<<<36864, 256, 0, stream>>>(rpb, btabf);

  temb_kernel<<<32, 128, 0, stream>>>(t_in, emb);
  smallmm_red<0><<<768, 256, 0, stream>>>(emb, t_w1, t_b1, h1, 256);
  smallmm_red<1><<<768, 256, 0, stream>>>(h1, t_w2, t_b2, xtb, 768);
  gemm128<3><<<dim3(216, 1), 256, 0, stream>>>(
      xtb, 768, wtT, 768, 768, bqt, bkt, bvt, nullptr, nullptr, nullptr,
      nullptr, ttok, nullptr, 0);

  patch_embed<<<24576, 256, 0, stream>>>(x, patch_w, patch_b, pos, xs);

  for (int l = 0; l < 12; ++l) {
    ln_bf16_kernel<<<8192, 256, 0, stream>>>(xs, norm1_w + l * 768, norm1_b + l * 768, hbuf);
    gemm128<0><<<dim3(18, 64), 256, 0, stream>>>(
        hbuf, 768, wqkvT + (size_t)l * 2304 * 768, 768, 768,
        bqs + l * 768, bks + l * 768, bvs + l * 768,
        ttok + (size_t)(l * 3 + 0) * 32 * 768,
        ttok + (size_t)(l * 3 + 1) * 32 * 768,
        ttok + (size_t)(l * 3 + 2) * 32 * 768,
        nullptr, nullptr, qkvb, 2304);
    attn_mfma<<<384, 256, 0, stream>>>(qkvb, btabf + (size_t)l * 12 * 65536, obuf);
    gemm128<1><<<dim3(6, 64), 256, 0, stream>>>(
        obuf, 768, projT + (size_t)l * 768 * 768, 768, 768,
        projb + l * 768, nullptr, nullptr, nullptr, nullptr, nullptr,
        xs, xs, nullptr, 768);
    ln_bf16_kernel<<<8192, 256, 0, stream>>>(xs, norm2_w + l * 768, norm2_b + l * 768, hbuf);
    gemm128<2><<<dim3(24, 64), 256, 0, stream>>>(
        hbuf, 768, mlp1T + (size_t)l * 3072 * 768, 768, 768,
        mlp_b1 + l * 3072, nullptr, nullptr, nullptr, nullptr, nullptr,
        nullptr, nullptr, hmlp, 3072);
    gemm128<1><<<dim3(6, 64), 256, 0, stream>>>(
        hmlp, 3072, mlp2T + (size_t)l * 768 * 3072, 3072, 3072,
        mlp_b2 + l * 768, nullptr, nullptr, nullptr, nullptr, nullptr,
        xs, xs, nullptr, 768);
  }
  ln_bf16_kernel<<<8192, 256, 0, stream>>>(xs, norm_w, norm_b, hbuf);
  gemm128<4><<<dim3(1, 64), 256, 0, stream>>>(
      hbuf, 768, dwT, 768, 768, dec_b, nullptr, nullptr, nullptr, nullptr, nullptr,
      nullptr, (float*)d_out, nullptr, 0);
}